// Round 12
// baseline (274.838 us; speedup 1.0000x reference)
//
#include <hip/hip_runtime.h>
#include <hip/hip_bf16.h>
#include <math.h>

#define S_TOT 20000
#define Q_TOT 32
#define N_TOT 200000
#define T_MAX 30
#define G_TOT 64
#define D_IN 300
#define H_DIM 256
#define D_SV 64
#define D_LANG 64
#define D_FUSE 128
#define D_CAT 67
#define FW_LD 131
#define SCHUNK 32
#define NBLK3 (S_TOT / SCHUNK)   // 625
#define SENT64 0xFFFFFFFFFFFFFFFFull
#define OUT_GRID 2048
#define PCHUNK 16
#define PTILES 40
#define GRU_T 512

// k_gi GEMM tiling: M=960, N=768, K=300
#define GI_MT 32
#define GI_NT 64
#define GI_KC 100
#define GI_NB 12
#define GI_GRID (30 * GI_NB)     // 360

__device__ __forceinline__ float sigmoidf_(float x) { return 1.0f / (1.0f + expf(-x)); }
__device__ __forceinline__ unsigned long long pack2(float a, float b) {
    return ((unsigned long long)__float_as_uint(b) << 32) | (unsigned long long)__float_as_uint(a);
}

// ---------------------------------------------------------------- k_gi: gi = x @ W_ih^T + b_ih
__global__ __launch_bounds__(128) void k_gi(const float* __restrict__ lang_feat,
                                            const float* __restrict__ w_ih,
                                            const float* __restrict__ b_ih,
                                            const float* __restrict__ fuse_w,
                                            const float* __restrict__ sqz_w1,
                                            const float* __restrict__ sqz_w2,
                                            const float* __restrict__ heat_w,
                                            float* __restrict__ gi,
                                            float* __restrict__ fwt,
                                            float* __restrict__ w1t,
                                            float* __restrict__ w2t,
                                            float* __restrict__ wdr) {
    const int tid = threadIdx.x;
    if (blockIdx.x >= GI_GRID) {
        for (int i = tid; i < FW_LD * D_FUSE; i += 128)
            fwt[(i % FW_LD) * D_FUSE + (i / FW_LD)] = fuse_w[i];
        for (int i = tid; i < D_LANG * H_DIM; i += 128)
            w1t[(i & 255) * D_LANG + (i >> 8)] = sqz_w1[i];
        for (int i = tid; i < D_LANG * D_LANG; i += 128)
            w2t[(i & 63) * D_LANG + (i >> 6)] = sqz_w2[i];
        if (tid < D_FUSE) wdr[tid] = heat_w[D_FUSE + tid] - heat_w[tid];
        return;
    }
    __shared__ float x_l[GI_KC][GI_MT + 1];
    __shared__ float w_l[GI_KC][GI_NT + 1];
    const int mb = blockIdx.x / GI_NB, nb = blockIdx.x % GI_NB;
    const int m0 = mb * GI_MT, n0 = nb * GI_NT;
    const int tq4 = (tid >> 4) * 4, jq4 = (tid & 15) * 4;

    float acc[4][4];
    #pragma unroll
    for (int i = 0; i < 4; ++i)
        #pragma unroll
        for (int j = 0; j < 4; ++j) acc[i][j] = 0.f;

    for (int kc = 0; kc < 3; ++kc) {
        const int k0 = kc * GI_KC;
        for (int i = tid; i < GI_MT * GI_KC; i += 128) {
            const int r = i / GI_KC, k = i % GI_KC;
            const int row = m0 + r, q = row / T_MAX, t = row - q * T_MAX;
            x_l[k][r] = lang_feat[(q * T_MAX + t) * D_IN + k0 + k];
        }
        for (int i = tid; i < GI_NT * GI_KC; i += 128) {
            const int r = i / GI_KC, k = i % GI_KC;
            w_l[k][r] = w_ih[(n0 + r) * D_IN + k0 + k];
        }
        __syncthreads();
        #pragma unroll 2
        for (int k = 0; k < GI_KC; ++k) {
            const float x0 = x_l[k][tq4 + 0], x1 = x_l[k][tq4 + 1];
            const float x2 = x_l[k][tq4 + 2], x3 = x_l[k][tq4 + 3];
            const float v0 = w_l[k][jq4 + 0], v1 = w_l[k][jq4 + 1];
            const float v2 = w_l[k][jq4 + 2], v3 = w_l[k][jq4 + 3];
            acc[0][0] = fmaf(x0, v0, acc[0][0]); acc[0][1] = fmaf(x0, v1, acc[0][1]);
            acc[0][2] = fmaf(x0, v2, acc[0][2]); acc[0][3] = fmaf(x0, v3, acc[0][3]);
            acc[1][0] = fmaf(x1, v0, acc[1][0]); acc[1][1] = fmaf(x1, v1, acc[1][1]);
            acc[1][2] = fmaf(x1, v2, acc[1][2]); acc[1][3] = fmaf(x1, v3, acc[1][3]);
            acc[2][0] = fmaf(x2, v0, acc[2][0]); acc[2][1] = fmaf(x2, v1, acc[2][1]);
            acc[2][2] = fmaf(x2, v2, acc[2][2]); acc[2][3] = fmaf(x2, v3, acc[2][3]);
            acc[3][0] = fmaf(x3, v0, acc[3][0]); acc[3][1] = fmaf(x3, v1, acc[3][1]);
            acc[3][2] = fmaf(x3, v2, acc[3][2]); acc[3][3] = fmaf(x3, v3, acc[3][3]);
        }
        __syncthreads();
    }
    const float b0 = b_ih[n0 + jq4 + 0], b1 = b_ih[n0 + jq4 + 1];
    const float b2 = b_ih[n0 + jq4 + 2], b3 = b_ih[n0 + jq4 + 3];
    #pragma unroll
    for (int i = 0; i < 4; ++i) {
        const int row = m0 + tq4 + i;
        const int q = row / T_MAX, t = row - q * T_MAX;
        float4 v = make_float4(acc[i][0] + b0, acc[i][1] + b1, acc[i][2] + b2, acc[i][3] + b3);
        *(float4*)&gi[(q * T_MAX + t) * 768 + n0 + jq4] = v;
    }
}

// ---------------------------------------------------------------- cooperative GRU, 512 thr, 1 barrier/step
// 16-lane group per h-index: lanes 0-3 r-dot, 4-7 z-dot, 8-11 n-dot, 12-15 shadow gate-2
// (identical addresses -> pure broadcast). Gate sums gathered via shfl_down(4/8) -> no ghl,
// no second barrier. hlq double-buffered so one barrier/step is hazard-free.
__global__ __launch_bounds__(GRU_T, 1) void k_gru512(const float* __restrict__ gi,
                                                     const float* __restrict__ w_hh,
                                                     const float* __restrict__ b_hh,
                                                     const int* __restrict__ lang_len,
                                                     float* __restrict__ hg,      // [30][32][256]
                                                     float* __restrict__ hbuf) {  // [32][256]
    __shared__ __align__(16) float wlds[96 * 256];
    __shared__ __align__(16) float hlq[2][4 * 68];
    __shared__ float gil[T_MAX * 96];

    const int tid = threadIdx.x;
    const int q = blockIdx.x >> 3, b = blockIdx.x & 7;
    int len = lang_len[q]; if (len > T_MAX) len = T_MAX; if (len < 1) len = 1;

    {   // swizzled weight staging: row R = hidx*3+gate; float4 col c at c ^ (R&7) ^ 2*(c>>4)
        const float4* src4 = (const float4*)w_hh;
        float4* dst4 = (float4*)wlds;
        for (int i = tid; i < 96 * 64; i += GRU_T) {
            const int R = i >> 6, c = i & 63;
            const int hx = R / 3, g8 = R - hx * 3;
            const int grow = (g8 << 8) + (b << 5) + hx;
            dst4[R * 64 + (c ^ (R & 7) ^ (((c >> 4) & 3) << 1))] = src4[grow * 64 + c];
        }
    }
    for (int i = tid; i < len * 96; i += GRU_T) {
        const int t = i / 96, r = i % 96;
        gil[i] = gi[(q * T_MAX + t) * 768 + ((r >> 5) << 8) + (b << 5) + (r & 31)];
    }
    __syncthreads();

    // step 0: h0 = 0 => gh = b_hh
    float h0new = 0.f;
    if (tid < 32) {
        const float bhr = b_hh[(b << 5) + tid];
        const float bhz = b_hh[H_DIM + (b << 5) + tid];
        const float bhn = b_hh[2 * H_DIM + (b << 5) + tid];
        const float r = sigmoidf_(gil[tid] + bhr);
        const float z = sigmoidf_(gil[32 + tid] + bhz);
        const float n = tanhf(gil[64 + tid] + r * bhn);
        h0new = (1.f - z) * n;
        if (len == 1) hbuf[q * H_DIM + (b << 5) + tid] = h0new;
    }
    if (tid < 64 && len > 1) {
        const float a0 = __shfl(h0new, 2 * (tid & 15));
        const float a1 = __shfl(h0new, 2 * (tid & 15) + 1);
        if (tid < 16) {
            unsigned long long* dst = (unsigned long long*)(hg + q * H_DIM + (b << 5));
            __hip_atomic_store(dst + tid, pack2(a0, a1), __ATOMIC_RELAXED, __HIP_MEMORY_SCOPE_AGENT);
        }
    }

    const int hidx = tid >> 4;
    const int gate0 = (tid >> 2) & 3;
    const int gateC = (gate0 == 3) ? 2 : gate0;
    const int ql = tid & 3;
    const int R = hidx * 3 + gateC;
    const int rx = R & 7;
    const int qx = ql << 1;
    const float4* wrow4 = (const float4*)wlds + R * 64;
    const int cbase = ql << 4;
    const float bh = b_hh[(gateC << 8) + (b << 5) + hidx];
    const bool base = ((tid & 15) == 0);
    const int kown = (b << 5) + hidx;

    for (int t = 1; t < len; ++t) {
        float* hl = hlq[t & 1];
        if (tid < 128) {   // poll previous-step h (data itself is the flag)
            const unsigned long long* src =
                (const unsigned long long*)(hg + (size_t)(t - 1) * (Q_TOT * H_DIM) + q * H_DIM);
            unsigned long long v;
            while ((v = __hip_atomic_load(src + tid, __ATOMIC_RELAXED,
                                          __HIP_MEMORY_SCOPE_AGENT)) == SENT64)
                __builtin_amdgcn_s_sleep(1);
            const int k = 2 * tid;
            const int o = (k >> 6) * 68 + (k & 63);
            hl[o]     = __uint_as_float((unsigned)(v & 0xffffffffu));
            hl[o + 1] = __uint_as_float((unsigned)(v >> 32));
        }
        __syncthreads();
        const float4* h4 = (const float4*)(hl + ql * 68);
        float ax = 0.f, ay = 0.f, az = 0.f, aw = 0.f;
        #pragma unroll
        for (int i = 0; i < 16; ++i) {
            const float4 wv = wrow4[((cbase + i) ^ rx) ^ qx];
            const float4 hv = h4[i];
            ax = fmaf(wv.x, hv.x, ax);
            ay = fmaf(wv.y, hv.y, ay);
            az = fmaf(wv.z, hv.z, az);
            aw = fmaf(wv.w, hv.w, aw);
        }
        float s = (ax + ay) + (az + aw);
        s += __shfl_xor(s, 1);
        s += __shfl_xor(s, 2);
        s += bh;
        const float sz = __shfl_down(s, 4);
        const float sn = __shfl_down(s, 8);
        float hnew = 0.f;
        if (base) {
            const float* gt_ = gil + t * 96;
            const float r = sigmoidf_(gt_[hidx] + s);
            const float z = sigmoidf_(gt_[32 + hidx] + sz);
            const float n = tanhf(gt_[64 + hidx] + r * sn);
            const float hold = hl[(kown >> 6) * 68 + (kown & 63)];
            hnew = (1.f - z) * n + z * hold;
            if (t == len - 1) hbuf[q * H_DIM + kown] = hnew;
        }
        if (t < len - 1) {
            const float a1 = __shfl_down(hnew, 16);
            if (base && ((hidx & 1) == 0)) {
                unsigned long long* dst =
                    (unsigned long long*)(hg + (size_t)t * (Q_TOT * H_DIM) + q * H_DIM + (b << 5));
                __hip_atomic_store(dst + (hidx >> 1), pack2(hnew, a1),
                                   __ATOMIC_RELAXED, __HIP_MEMORY_SCOPE_AGENT);
            }
        }
    }
}

// ---------------------------------------------------------------- lang head, one block per query
__global__ __launch_bounds__(256) void k_lang(const float* __restrict__ hbuf,
                                              const float* __restrict__ w1t, const float* __restrict__ b1,
                                              const float* __restrict__ w2t, const float* __restrict__ b2,
                                              const float* __restrict__ fwt, const float* __restrict__ fuse_b,
                                              float* __restrict__ langc) {
    __shared__ float hql[H_DIM];
    __shared__ float t1l[D_LANG];
    __shared__ float lgl[D_LANG];
    const int q = blockIdx.x, tid = threadIdx.x;
    hql[tid] = hbuf[q * H_DIM + tid];
    __syncthreads();
    {
        const int c = tid >> 2, ql = tid & 3;
        float a = 0.f;
        #pragma unroll 8
        for (int j = 0; j < 64; ++j) {
            const int k = (ql << 6) + j;
            a = fmaf(w1t[k * D_LANG + c], hql[k], a);
        }
        a += __shfl_xor(a, 1);
        a += __shfl_xor(a, 2);
        if (ql == 0) t1l[c] = fmaxf(a + b1[c], 0.f);
    }
    __syncthreads();
    {
        const int c = tid >> 2, ql = tid & 3;
        float a = 0.f;
        #pragma unroll
        for (int j = 0; j < 16; ++j) {
            const int k = (ql << 4) + j;
            a = fmaf(w2t[k * D_LANG + c], t1l[k], a);
        }
        a += __shfl_xor(a, 1);
        a += __shfl_xor(a, 2);
        if (ql == 0) lgl[c] = a + b2[c];
    }
    __syncthreads();
    {
        const int d = tid >> 1, hh = tid & 1;
        float a = 0.f;
        #pragma unroll 8
        for (int j = 0; j < 32; ++j) {
            const int k = (hh << 5) + j;
            a = fmaf(fwt[(D_CAT + k) * D_FUSE + d], lgl[k], a);
        }
        a += __shfl_xor(a, 1);
        if (hh == 0) langc[q * D_FUSE + d] = a + fuse_b[d];
    }
}

// ---------------------------------------------------------------- fused sv_proj + score + group partials
__global__ __launch_bounds__(256) void k_fuse(const float* __restrict__ feat,
                                              const float* __restrict__ coords,
                                              const int* __restrict__ grps,
                                              const float* __restrict__ langc,
                                              const float* __restrict__ fwt,
                                              const float* __restrict__ wdr_g,
                                              const float* __restrict__ heat_b,
                                              float* __restrict__ grp_part,
                                              int* __restrict__ cnt_part) {
    __shared__ __align__(16) float svin[SCHUNK][68];
    __shared__ __align__(16) float svp[SCHUNK][132];
    __shared__ float score[SCHUNK][Q_TOT];
    __shared__ int grps_l[SCHUNK];
    const int tid = threadIdx.x;
    const int s0 = blockIdx.x * SCHUNK;

    const int dsl = tid & 7, q = tid >> 3;     // 8 x 32
    float lc[16], wdr[16];
    #pragma unroll
    for (int i = 0; i < 16; ++i) {
        const int d = dsl * 16 + i;
        lc[i]  = langc[q * D_FUSE + d];
        wdr[i] = wdr_g[d];
    }
    const float hbd = heat_b[1] - heat_b[0];

    for (int i = tid; i < SCHUNK * D_SV; i += 256) {
        const int r = i >> 6, c = i & 63;
        svin[r][c] = feat[(s0 + r) * D_SV + c];
    }
    if (tid < SCHUNK * 3) { const int r = tid / 3, c = tid % 3; svin[r][D_SV + c] = coords[(s0 + r) * 3 + c]; }
    if (tid < SCHUNK) grps_l[tid] = grps[s0 + tid];
    __syncthreads();

    {   // sv_proj, k-blocked by 4, b128 svin reads
        const int d = tid & 127, sl0 = tid >> 7;
        float acc[16];
        #pragma unroll
        for (int i = 0; i < 16; ++i) acc[i] = 0.f;
        for (int k4 = 0; k4 < 16; ++k4) {
            const float w0 = fwt[(4 * k4 + 0) * D_FUSE + d];
            const float w1 = fwt[(4 * k4 + 1) * D_FUSE + d];
            const float w2 = fwt[(4 * k4 + 2) * D_FUSE + d];
            const float w3 = fwt[(4 * k4 + 3) * D_FUSE + d];
            #pragma unroll
            for (int i = 0; i < 16; ++i) {
                const float4 xv = *(const float4*)&svin[sl0 + 2 * i][4 * k4];
                acc[i] = fmaf(xv.x, w0, fmaf(xv.y, w1, fmaf(xv.z, w2, fmaf(xv.w, w3, acc[i]))));
            }
        }
        for (int k = 64; k < D_CAT; ++k) {
            const float wv = fwt[k * D_FUSE + d];
            #pragma unroll
            for (int i = 0; i < 16; ++i)
                acc[i] = fmaf(svin[sl0 + 2 * i][k], wv, acc[i]);
        }
        #pragma unroll
        for (int i = 0; i < 16; ++i) svp[sl0 + 2 * i][d] = acc[i];
    }
    __syncthreads();

    for (int sl = 0; sl < SCHUNK; ++sl) {
        const float4* sv4 = (const float4*)(&svp[sl][dsl * 16]);
        float part = 0.f;
        #pragma unroll
        for (int j = 0; j < 4; ++j) {
            const float4 v = sv4[j];
            part = fmaf(fmaxf(v.x + lc[4*j+0], 0.f), wdr[4*j+0], part);
            part = fmaf(fmaxf(v.y + lc[4*j+1], 0.f), wdr[4*j+1], part);
            part = fmaf(fmaxf(v.z + lc[4*j+2], 0.f), wdr[4*j+2], part);
            part = fmaf(fmaxf(v.w + lc[4*j+3], 0.f), wdr[4*j+3], part);
        }
        part += __shfl_xor(part, 1);
        part += __shfl_xor(part, 2);
        part += __shfl_xor(part, 4);
        if (dsl == 0) score[sl][q] = sigmoidf_(part + hbd);
    }
    __syncthreads();

    for (int i = 0; i < 8; ++i) {
        const int cell = tid + 256 * i;            // q*64+g
        const int qq = cell >> 6, g = cell & 63;
        float sum = 0.f;
        #pragma unroll
        for (int sl = 0; sl < SCHUNK; ++sl)
            sum += (grps_l[sl] == g) ? score[sl][qq] : 0.f;
        grp_part[blockIdx.x * (Q_TOT * G_TOT) + cell] = sum;
        if (cell < G_TOT) {
            int c = 0;
            #pragma unroll
            for (int sl = 0; sl < SCHUNK; ++sl) c += (grps_l[sl] == g);
            cnt_part[blockIdx.x * G_TOT + g] = c;
        }
    }
}

// ---------------------------------------------------------------- two-stage reduction + argmax + smask
__global__ __launch_bounds__(256) void k_post(const float* __restrict__ grp_part,
                                              const int* __restrict__ cnt_part,
                                              const int* __restrict__ grps,
                                              float* __restrict__ grp2,
                                              int* __restrict__ cnt2,
                                              int* __restrict__ best,
                                              int* __restrict__ smask,
                                              int* __restrict__ qtick,
                                              int* __restrict__ gtick) {
    __shared__ float ps[4][G_TOT];
    __shared__ int   pc[4][G_TOT];
    __shared__ float sc[G_TOT];
    __shared__ int bl[Q_TOT];
    __shared__ int myturn, lastq;
    const int tid = threadIdx.x;
    const int q = blockIdx.x & 31, c = blockIdx.x >> 5;
    const int bq = tid >> 6, g = tid & 63;
    const int b0 = c * PTILES;
    int b1 = b0 + PTILES; if (b1 > NBLK3) b1 = NBLK3;

    float acc = 0.f; int cacc = 0;
    for (int b = b0 + bq; b < b1; b += 4) {
        acc  += grp_part[b * (Q_TOT * G_TOT) + q * G_TOT + g];
        cacc += cnt_part[b * G_TOT + g];
    }
    ps[bq][g] = acc; pc[bq][g] = cacc;
    __syncthreads();
    if (tid < G_TOT) {
        const float s = ((ps[0][tid] + ps[1][tid]) + ps[2][tid]) + ps[3][tid];
        const int  cc = ((pc[0][tid] + pc[1][tid]) + pc[2][tid]) + pc[3][tid];
        __hip_atomic_store(&grp2[(c * Q_TOT + q) * G_TOT + tid], s,
                           __ATOMIC_RELAXED, __HIP_MEMORY_SCOPE_AGENT);
        __hip_atomic_store(&cnt2[(c * Q_TOT + q) * G_TOT + tid], cc,
                           __ATOMIC_RELAXED, __HIP_MEMORY_SCOPE_AGENT);
    }
    asm volatile("s_waitcnt vmcnt(0)" ::: "memory");
    if (tid == 0) {
        const int old = __hip_atomic_fetch_add(&qtick[q], 1, __ATOMIC_RELAXED, __HIP_MEMORY_SCOPE_AGENT);
        myturn = (old == PCHUNK - 1) ? 1 : 0;
    }
    __syncthreads();
    if (!myturn) return;

    if (tid < G_TOT) {
        float s = 0.f; int cc = 0;
        #pragma unroll
        for (int c2 = 0; c2 < PCHUNK; ++c2) {
            s  += __hip_atomic_load(&grp2[(c2 * Q_TOT + q) * G_TOT + tid],
                                    __ATOMIC_RELAXED, __HIP_MEMORY_SCOPE_AGENT);
            cc += __hip_atomic_load(&cnt2[(c2 * Q_TOT + q) * G_TOT + tid],
                                    __ATOMIC_RELAXED, __HIP_MEMORY_SCOPE_AGENT);
        }
        sc[tid] = s / (float)cc;
    }
    __syncthreads();
    if (tid == 0) {
        float bv = sc[0]; int bi = 0;
        for (int g2 = 1; g2 < G_TOT; ++g2) if (sc[g2] > bv) { bv = sc[g2]; bi = g2; }
        __hip_atomic_store(&best[q], bi, __ATOMIC_RELAXED, __HIP_MEMORY_SCOPE_AGENT);
        asm volatile("s_waitcnt vmcnt(0)" ::: "memory");
        const int old = __hip_atomic_fetch_add(gtick, 1, __ATOMIC_RELAXED, __HIP_MEMORY_SCOPE_AGENT);
        lastq = (old == Q_TOT - 1) ? 1 : 0;
    }
    __syncthreads();
    if (!lastq) return;
    if (tid < Q_TOT) bl[tid] = __hip_atomic_load(&best[tid], __ATOMIC_RELAXED, __HIP_MEMORY_SCOPE_AGENT);
    __syncthreads();
    for (int s = tid; s < S_TOT; s += 256) {
        const int gg = grps[s];
        int m = 0;
        #pragma unroll
        for (int qq = 0; qq < Q_TOT; ++qq) m |= (bl[qq] == gg) ? (1 << qq) : 0;
        smask[s] = m;
    }
}

// ---------------------------------------------------------------- obj_pts + inter/union + iou (vectorized)
__global__ __launch_bounds__(256) void k_out(const int* __restrict__ supervox,
                                             const int* __restrict__ gt,
                                             const int* __restrict__ smask,
                                             float* __restrict__ out,
                                             int* __restrict__ interG, int* __restrict__ unionG,
                                             int* __restrict__ ticket) {
    const int tid = threadIdx.x;
    const int gidx = blockIdx.x * 256 + tid;
    const int q4 = (gidx & 7) * 4;
    const int nstride = (OUT_GRID * 256) >> 3;   // 65536
    int a0 = 0, a1 = 0, a2 = 0, a3 = 0;
    int u0 = 0, u1 = 0, u2 = 0, u3 = 0;
    for (int n = gidx >> 3; n < N_TOT; n += nstride) {
        const int m = smask[supervox[n]];
        const int4 g4 = *(const int4*)&gt[n * Q_TOT + q4];
        const int o0 = (m >> (q4 + 0)) & 1;
        const int o1 = (m >> (q4 + 1)) & 1;
        const int o2 = (m >> (q4 + 2)) & 1;
        const int o3 = (m >> (q4 + 3)) & 1;
        *(float4*)&out[n * Q_TOT + q4] =
            make_float4((float)o0, (float)o1, (float)o2, (float)o3);
        a0 += o0 & g4.x; u0 += o0 | g4.x;
        a1 += o1 & g4.y; u1 += o1 | g4.y;
        a2 += o2 & g4.z; u2 += o2 | g4.z;
        a3 += o3 & g4.w; u3 += o3 | g4.w;
    }
    __shared__ int bi[Q_TOT], bu[Q_TOT];
    __shared__ int islast;
    if (tid < Q_TOT) { bi[tid] = 0; bu[tid] = 0; }
    __syncthreads();
    atomicAdd(&bi[q4 + 0], a0); atomicAdd(&bu[q4 + 0], u0);
    atomicAdd(&bi[q4 + 1], a1); atomicAdd(&bu[q4 + 1], u1);
    atomicAdd(&bi[q4 + 2], a2); atomicAdd(&bu[q4 + 2], u2);
    atomicAdd(&bi[q4 + 3], a3); atomicAdd(&bu[q4 + 3], u3);
    __syncthreads();
    if (tid < Q_TOT) { atomicAdd(&interG[tid], bi[tid]); atomicAdd(&unionG[tid], bu[tid]); }
    asm volatile("s_waitcnt vmcnt(0)" ::: "memory");
    if (tid == 0) {
        const int old = __hip_atomic_fetch_add(ticket, 1, __ATOMIC_RELAXED, __HIP_MEMORY_SCOPE_AGENT);
        islast = (old == OUT_GRID - 1) ? 1 : 0;
    }
    __syncthreads();
    if (islast && tid < Q_TOT) {
        const int iv = __hip_atomic_load(&interG[tid], __ATOMIC_RELAXED, __HIP_MEMORY_SCOPE_AGENT);
        const int uv = __hip_atomic_load(&unionG[tid], __ATOMIC_RELAXED, __HIP_MEMORY_SCOPE_AGENT);
        out[(size_t)N_TOT * Q_TOT + tid] = (float)iv / ((float)uv + 1e-5f);
    }
}

extern "C" void kernel_launch(void* const* d_in, const int* in_sizes, int n_in,
                              void* d_out, int out_size, void* d_ws, size_t ws_size,
                              hipStream_t stream) {
    const float* lang_feat = (const float*)d_in[0];
    const float* feat      = (const float*)d_in[1];
    const float* coords    = (const float*)d_in[2];
    const int*   lang_len  = (const int*)d_in[3];
    const int*   grps      = (const int*)d_in[4];
    const int*   supervox  = (const int*)d_in[5];
    const int*   gt        = (const int*)d_in[6];
    const float* w_ih      = (const float*)d_in[7];
    const float* w_hh      = (const float*)d_in[8];
    const float* b_ih      = (const float*)d_in[9];
    const float* b_hh      = (const float*)d_in[10];
    const float* sqz_w1    = (const float*)d_in[11];
    const float* sqz_b1    = (const float*)d_in[12];
    const float* sqz_w2    = (const float*)d_in[13];
    const float* sqz_b2    = (const float*)d_in[14];
    const float* fuse_w    = (const float*)d_in[15];
    const float* fuse_b    = (const float*)d_in[16];
    const float* heat_w    = (const float*)d_in[17];
    const float* heat_b    = (const float*)d_in[18];
    float* out = (float*)d_out;

    float* gi       = (float*)d_ws;                       // 737280
    float* hbuf     = gi + 737280;                        // 8192
    float* langc    = hbuf + 8192;                        // 4096
    float* grp_part = langc + 4096;                       // 1280000
    int*   cnt_part = (int*)(grp_part + NBLK3 * 2048);    // 40000
    int*   best     = cnt_part + NBLK3 * 64;              // 32
    int*   smask    = best + 32;                          // 20000
    int*   syncs    = smask + S_TOT;                      // 128: interG|unionG|tickets|qtick
    float* hg       = (float*)(syncs + 128);              // 245760
    float* fwt      = hg + 30 * Q_TOT * H_DIM;            // 16768
    float* w1t      = fwt + FW_LD * D_FUSE;               // 16384
    float* w2t      = w1t + H_DIM * D_LANG;               // 4096
    float* wdr      = w2t + D_LANG * D_LANG;              // 128
    float* grp2     = wdr + 128;                          // 32768
    int*   cnt2     = (int*)(grp2 + PCHUNK * Q_TOT * G_TOT); // 32768

    hipMemsetAsync(syncs, 0, 128 * sizeof(int), stream);
    hipMemsetAsync(hg, 0xFF, (size_t)30 * Q_TOT * H_DIM * sizeof(float), stream);

    k_gi    <<<GI_GRID + 1, 128, 0, stream>>>(lang_feat, w_ih, b_ih, fuse_w, sqz_w1, sqz_w2, heat_w,
                                              gi, fwt, w1t, w2t, wdr);
    k_gru512<<<Q_TOT * 8, GRU_T, 0, stream>>>(gi, w_hh, b_hh, lang_len, hg, hbuf);
    k_lang  <<<Q_TOT, 256, 0, stream>>>(hbuf, w1t, sqz_b1, w2t, sqz_b2, fwt, fuse_b, langc);
    k_fuse  <<<NBLK3, 256, 0, stream>>>(feat, coords, grps, langc, fwt, wdr, heat_b,
                                        grp_part, cnt_part);
    k_post  <<<Q_TOT * PCHUNK, 256, 0, stream>>>(grp_part, cnt_part, grps, grp2, cnt2,
                                                 best, smask, syncs + 96, syncs + 65);
    k_out   <<<OUT_GRID, 256, 0, stream>>>(supervox, gt, smask, out, syncs, syncs + 32, syncs + 64);
}

// Round 13
// 249.506 us; speedup vs baseline: 1.1015x; 1.1015x over previous
//
#include <hip/hip_runtime.h>
#include <hip/hip_bf16.h>
#include <math.h>

#define S_TOT 20000
#define Q_TOT 32
#define N_TOT 200000
#define T_MAX 30
#define G_TOT 64
#define D_IN 300
#define H_DIM 256
#define D_SV 64
#define D_LANG 64
#define D_FUSE 128
#define D_CAT 67
#define FW_LD 131
#define SCHUNK 32
#define NBLK3 (S_TOT / SCHUNK)   // 625
#define SENT64 0xFFFFFFFFFFFFFFFFull
#define OUT_GRID 2048
#define PCHUNK 16
#define PTILES 40

// k_gi GEMM tiling: M=960, N=768, K=300
#define GI_MT 32
#define GI_NT 64
#define GI_KC 100
#define GI_NB 12
#define GI_GRID (30 * GI_NB)     // 360
#define HG_ELEMS (30 * Q_TOT * H_DIM)

// syncs layout (ints): [0..31] interG | [32..63] unionG | [64] out-ticket | [65] gtick
//                      [66..97] qdone (gru->lang) | [98..129] qtick (post)
#define SYNCS_N 160

__device__ __forceinline__ float sigmoidf_(float x) { return 1.0f / (1.0f + expf(-x)); }
__device__ __forceinline__ unsigned long long pack2(float a, float b) {
    return ((unsigned long long)__float_as_uint(b) << 32) | (unsigned long long)__float_as_uint(a);
}

// ---------------------------------------------------------------- k_gi: gi = x @ W_ih^T + b_ih
// blocks 0..359: GEMM tiles; 360: weight transposes; 361..368: hg sentinel fill (+syncs zero)
__global__ __launch_bounds__(128) void k_gi(const float* __restrict__ lang_feat,
                                            const float* __restrict__ w_ih,
                                            const float* __restrict__ b_ih,
                                            const float* __restrict__ fuse_w,
                                            const float* __restrict__ sqz_w1,
                                            const float* __restrict__ sqz_w2,
                                            const float* __restrict__ heat_w,
                                            float* __restrict__ gi,
                                            float* __restrict__ fwt,
                                            float* __restrict__ w1t,
                                            float* __restrict__ w2t,
                                            float* __restrict__ wdr,
                                            float* __restrict__ hg,
                                            int* __restrict__ syncs) {
    const int tid = threadIdx.x;
    if (blockIdx.x >= GI_GRID) {
        const int xb = blockIdx.x - GI_GRID;
        if (xb == 0) {
            for (int i = tid; i < FW_LD * D_FUSE; i += 128)
                fwt[(i % FW_LD) * D_FUSE + (i / FW_LD)] = fuse_w[i];
            for (int i = tid; i < D_LANG * H_DIM; i += 128)
                w1t[(i & 255) * D_LANG + (i >> 8)] = sqz_w1[i];
            for (int i = tid; i < D_LANG * D_LANG; i += 128)
                w2t[(i & 63) * D_LANG + (i >> 6)] = sqz_w2[i];
            if (tid < D_FUSE) wdr[tid] = heat_w[D_FUSE + tid] - heat_w[tid];
        } else {
            const int fb = xb - 1;                        // 0..7
            const int per4 = HG_ELEMS / 4 / 8;            // float4s per fill block
            float4* dst = (float4*)hg + fb * per4;
            const float4 sv = make_float4(__uint_as_float(0xFFFFFFFFu), __uint_as_float(0xFFFFFFFFu),
                                          __uint_as_float(0xFFFFFFFFu), __uint_as_float(0xFFFFFFFFu));
            for (int i = tid; i < per4; i += 128) dst[i] = sv;
            if (fb == 0) for (int i = tid; i < SYNCS_N; i += 128) syncs[i] = 0;
        }
        return;
    }
    __shared__ float x_l[GI_KC][GI_MT + 1];
    __shared__ float w_l[GI_KC][GI_NT + 1];
    const int mb = blockIdx.x / GI_NB, nb = blockIdx.x % GI_NB;
    const int m0 = mb * GI_MT, n0 = nb * GI_NT;
    const int tq4 = (tid >> 4) * 4, jq4 = (tid & 15) * 4;

    float acc[4][4];
    #pragma unroll
    for (int i = 0; i < 4; ++i)
        #pragma unroll
        for (int j = 0; j < 4; ++j) acc[i][j] = 0.f;

    for (int kc = 0; kc < 3; ++kc) {
        const int k0 = kc * GI_KC;
        for (int i = tid; i < GI_MT * GI_KC; i += 128) {
            const int r = i / GI_KC, k = i % GI_KC;
            const int row = m0 + r, q = row / T_MAX, t = row - q * T_MAX;
            x_l[k][r] = lang_feat[(q * T_MAX + t) * D_IN + k0 + k];
        }
        for (int i = tid; i < GI_NT * GI_KC; i += 128) {
            const int r = i / GI_KC, k = i % GI_KC;
            w_l[k][r] = w_ih[(n0 + r) * D_IN + k0 + k];
        }
        __syncthreads();
        #pragma unroll 2
        for (int k = 0; k < GI_KC; ++k) {
            const float x0 = x_l[k][tq4 + 0], x1 = x_l[k][tq4 + 1];
            const float x2 = x_l[k][tq4 + 2], x3 = x_l[k][tq4 + 3];
            const float v0 = w_l[k][jq4 + 0], v1 = w_l[k][jq4 + 1];
            const float v2 = w_l[k][jq4 + 2], v3 = w_l[k][jq4 + 3];
            acc[0][0] = fmaf(x0, v0, acc[0][0]); acc[0][1] = fmaf(x0, v1, acc[0][1]);
            acc[0][2] = fmaf(x0, v2, acc[0][2]); acc[0][3] = fmaf(x0, v3, acc[0][3]);
            acc[1][0] = fmaf(x1, v0, acc[1][0]); acc[1][1] = fmaf(x1, v1, acc[1][1]);
            acc[1][2] = fmaf(x1, v2, acc[1][2]); acc[1][3] = fmaf(x1, v3, acc[1][3]);
            acc[2][0] = fmaf(x2, v0, acc[2][0]); acc[2][1] = fmaf(x2, v1, acc[2][1]);
            acc[2][2] = fmaf(x2, v2, acc[2][2]); acc[2][3] = fmaf(x2, v3, acc[2][3]);
            acc[3][0] = fmaf(x3, v0, acc[3][0]); acc[3][1] = fmaf(x3, v1, acc[3][1]);
            acc[3][2] = fmaf(x3, v2, acc[3][2]); acc[3][3] = fmaf(x3, v3, acc[3][3]);
        }
        __syncthreads();
    }
    const float b0 = b_ih[n0 + jq4 + 0], b1 = b_ih[n0 + jq4 + 1];
    const float b2 = b_ih[n0 + jq4 + 2], b3 = b_ih[n0 + jq4 + 3];
    #pragma unroll
    for (int i = 0; i < 4; ++i) {
        const int row = m0 + tq4 + i;
        const int q = row / T_MAX, t = row - q * T_MAX;
        float4 v = make_float4(acc[i][0] + b0, acc[i][1] + b1, acc[i][2] + b2, acc[i][3] + b3);
        *(float4*)&gi[(q * T_MAX + t) * 768 + n0 + jq4] = v;
    }
}

// ---------------------------------------------------------------- cooperative GRU (R11 structure)
// + folded lang head: each block agent-stores its final h slice and bumps qdone[q];
//   the b==0 block polls qdone[q]==8, loads full h row, computes langc in-block.
__global__ __launch_bounds__(384, 1) void k_gru8(const float* __restrict__ gi,
                                                 const float* __restrict__ w_hh,
                                                 const float* __restrict__ b_hh,
                                                 const int* __restrict__ lang_len,
                                                 float* __restrict__ hg,      // [30][32][256]
                                                 float* __restrict__ hbuf,    // [32][256]
                                                 const float* __restrict__ w1t,
                                                 const float* __restrict__ b1,
                                                 const float* __restrict__ w2t,
                                                 const float* __restrict__ b2,
                                                 const float* __restrict__ fwt,
                                                 const float* __restrict__ fuse_b,
                                                 float* __restrict__ langc,
                                                 int* __restrict__ qdone) {
    __shared__ __align__(16) float wlds[96 * 256];
    __shared__ __align__(16) float hlq[4 * 68];
    __shared__ float ghl[96];
    __shared__ float gil[T_MAX * 96];    // also reused as hql/t1l/lgl scratch in lang epilogue

    const int tid = threadIdx.x;
    const int q = blockIdx.x >> 3, b = blockIdx.x & 7;
    int len = lang_len[q]; if (len > T_MAX) len = T_MAX; if (len < 1) len = 1;

    {   // swizzled weight staging: float4 col c of row r stored at c ^ (r&7)
        const float4* src4 = (const float4*)w_hh;
        float4* dst4 = (float4*)wlds;
        for (int i = tid; i < 96 * 64; i += 384) {
            const int r = i >> 6, c = i & 63;
            const int grow = ((r >> 5) << 8) + (b << 5) + (r & 31);
            dst4[r * 64 + (c ^ (r & 7))] = src4[grow * 64 + c];
        }
    }
    for (int i = tid; i < len * 96; i += 384) {
        const int t = i / 96, r = i % 96;
        gil[i] = gi[(q * T_MAX + t) * 768 + ((r >> 5) << 8) + (b << 5) + (r & 31)];
    }
    __syncthreads();

    float hfin = 0.f;
    // step 0: h0 = 0 => gh = b_hh
    {
        float hnew = 0.f;
        if (tid < 32) {
            const float bhr = b_hh[(b << 5) + tid];
            const float bhz = b_hh[H_DIM + (b << 5) + tid];
            const float bhn = b_hh[2 * H_DIM + (b << 5) + tid];
            const float r = sigmoidf_(gil[tid] + bhr);
            const float z = sigmoidf_(gil[32 + tid] + bhz);
            const float n = tanhf(gil[64 + tid] + r * bhn);
            hnew = (1.f - z) * n;
            if (len == 1) hfin = hnew;
        }
        if (tid < 64 && len > 1) {
            const float a0 = __shfl(hnew, 2 * (tid & 15));
            const float a1 = __shfl(hnew, 2 * (tid & 15) + 1);
            if (tid < 16) {
                unsigned long long* dst = (unsigned long long*)(hg + q * H_DIM + (b << 5));
                __hip_atomic_store(dst + tid, pack2(a0, a1), __ATOMIC_RELAXED, __HIP_MEMORY_SCOPE_AGENT);
            }
        }
    }

    const int row = tid >> 2, ql = tid & 3;
    const float bh = b_hh[((row >> 5) << 8) + (b << 5) + (row & 31)];
    const int rx = row & 7;
    const float4* wrow4 = (const float4*)wlds + row * 64;
    const int cbase = ql << 4;

    for (int t = 1; t < len; ++t) {
        if (tid < 128) {   // poll previous-step h (data itself is the flag)
            const unsigned long long* src =
                (const unsigned long long*)(hg + (size_t)(t - 1) * (Q_TOT * H_DIM) + q * H_DIM);
            unsigned long long v;
            while ((v = __hip_atomic_load(src + tid, __ATOMIC_RELAXED,
                                          __HIP_MEMORY_SCOPE_AGENT)) == SENT64)
                __builtin_amdgcn_s_sleep(1);
            const int k = 2 * tid;
            const int o = (k >> 6) * 68 + (k & 63);
            hlq[o]     = __uint_as_float((unsigned)(v & 0xffffffffu));
            hlq[o + 1] = __uint_as_float((unsigned)(v >> 32));
        }
        __syncthreads();
        float hold = 0.f;
        if (tid < 32) { const int k = (b << 5) + tid; hold = hlq[(k >> 6) * 68 + (k & 63)]; }
        const float4* h4 = (const float4*)(hlq + ql * 68);
        float ax = 0.f, ay = 0.f, az = 0.f, aw = 0.f;
        #pragma unroll
        for (int i = 0; i < 16; ++i) {
            const float4 wv = wrow4[(cbase + i) ^ rx];
            const float4 hv = h4[i];
            ax = fmaf(wv.x, hv.x, ax);
            ay = fmaf(wv.y, hv.y, ay);
            az = fmaf(wv.z, hv.z, az);
            aw = fmaf(wv.w, hv.w, aw);
        }
        float s = (ax + ay) + (az + aw);
        s += __shfl_xor(s, 1);
        s += __shfl_xor(s, 2);
        if (ql == 0) ghl[row] = s + bh;
        __syncthreads();
        float hnew = 0.f;
        if (tid < 32) {
            const float* gt_ = gil + t * 96;
            const float r = sigmoidf_(gt_[tid] + ghl[tid]);
            const float z = sigmoidf_(gt_[32 + tid] + ghl[32 + tid]);
            const float n = tanhf(gt_[64 + tid] + r * ghl[64 + tid]);
            hnew = (1.f - z) * n + z * hold;
            if (t == len - 1) hfin = hnew;
        }
        if (tid < 64 && t < len - 1) {
            const float a0 = __shfl(hnew, 2 * (tid & 15));
            const float a1 = __shfl(hnew, 2 * (tid & 15) + 1);
            if (tid < 16) {
                unsigned long long* dst =
                    (unsigned long long*)(hg + (size_t)t * (Q_TOT * H_DIM) + q * H_DIM + (b << 5));
                __hip_atomic_store(dst + tid, pack2(a0, a1), __ATOMIC_RELAXED, __HIP_MEMORY_SCOPE_AGENT);
            }
        }
    }

    // ---- epilogue: publish final h slice, count, b==0 computes lang head
    if (tid < 32)
        __hip_atomic_store(&hbuf[q * H_DIM + (b << 5) + tid], hfin,
                           __ATOMIC_RELAXED, __HIP_MEMORY_SCOPE_AGENT);
    asm volatile("s_waitcnt vmcnt(0)" ::: "memory");
    __syncthreads();
    if (tid == 0)
        __hip_atomic_fetch_add(&qdone[q], 1, __ATOMIC_RELAXED, __HIP_MEMORY_SCOPE_AGENT);
    if (b != 0) return;

    if (tid == 0) {
        while (__hip_atomic_load(&qdone[q], __ATOMIC_RELAXED, __HIP_MEMORY_SCOPE_AGENT) < 8)
            __builtin_amdgcn_s_sleep(2);
    }
    __syncthreads();
    float* hql = gil;            // 256
    float* t1l = gil + 256;      // 64
    float* lgl = gil + 320;      // 64
    if (tid < H_DIM)
        hql[tid] = __hip_atomic_load(&hbuf[q * H_DIM + tid], __ATOMIC_RELAXED, __HIP_MEMORY_SCOPE_AGENT);
    __syncthreads();
    if (tid < 256) {   // t1 = relu(w1.h + b1), 4 lanes per output
        const int c = tid >> 2, qq = tid & 3;
        float a = 0.f;
        #pragma unroll 8
        for (int j = 0; j < 64; ++j) {
            const int k = (qq << 6) + j;
            a = fmaf(w1t[k * D_LANG + c], hql[k], a);
        }
        a += __shfl_xor(a, 1);
        a += __shfl_xor(a, 2);
        if (qq == 0) t1l[c] = fmaxf(a + b1[c], 0.f);
    }
    __syncthreads();
    if (tid < 256) {   // lg = w2.t1 + b2
        const int c = tid >> 2, qq = tid & 3;
        float a = 0.f;
        #pragma unroll
        for (int j = 0; j < 16; ++j) {
            const int k = (qq << 4) + j;
            a = fmaf(w2t[k * D_LANG + c], t1l[k], a);
        }
        a += __shfl_xor(a, 1);
        a += __shfl_xor(a, 2);
        if (qq == 0) lgl[c] = a + b2[c];
    }
    __syncthreads();
    if (tid < 256) {   // langc = fuse_w[:,67:].lg + fuse_b
        const int d = tid >> 1, hh = tid & 1;
        float a = 0.f;
        #pragma unroll 8
        for (int j = 0; j < 32; ++j) {
            const int k = (hh << 5) + j;
            a = fmaf(fwt[(D_CAT + k) * D_FUSE + d], lgl[k], a);
        }
        a += __shfl_xor(a, 1);
        if (hh == 0) langc[q * D_FUSE + d] = a + fuse_b[d];
    }
}

// ---------------------------------------------------------------- fused sv_proj + score + group partials
__global__ __launch_bounds__(256) void k_fuse(const float* __restrict__ feat,
                                              const float* __restrict__ coords,
                                              const int* __restrict__ grps,
                                              const float* __restrict__ langc,
                                              const float* __restrict__ fwt,
                                              const float* __restrict__ wdr_g,
                                              const float* __restrict__ heat_b,
                                              float* __restrict__ grp_part,
                                              int* __restrict__ cnt_part) {
    __shared__ __align__(16) float svin[SCHUNK][68];
    __shared__ __align__(16) float svp[SCHUNK][132];
    __shared__ float score[SCHUNK][Q_TOT];
    __shared__ int grps_l[SCHUNK];
    const int tid = threadIdx.x;
    const int s0 = blockIdx.x * SCHUNK;

    const int dsl = tid & 7, q = tid >> 3;     // 8 x 32
    float lc[16], wdr[16];
    #pragma unroll
    for (int i = 0; i < 16; ++i) {
        const int d = dsl * 16 + i;
        lc[i]  = langc[q * D_FUSE + d];
        wdr[i] = wdr_g[d];
    }
    const float hbd = heat_b[1] - heat_b[0];

    for (int i = tid; i < SCHUNK * D_SV; i += 256) {
        const int r = i >> 6, c = i & 63;
        svin[r][c] = feat[(s0 + r) * D_SV + c];
    }
    if (tid < SCHUNK * 3) { const int r = tid / 3, c = tid % 3; svin[r][D_SV + c] = coords[(s0 + r) * 3 + c]; }
    if (tid < SCHUNK) grps_l[tid] = grps[s0 + tid];
    __syncthreads();

    {   // sv_proj, k-blocked by 4, b128 svin reads
        const int d = tid & 127, sl0 = tid >> 7;
        float acc[16];
        #pragma unroll
        for (int i = 0; i < 16; ++i) acc[i] = 0.f;
        for (int k4 = 0; k4 < 16; ++k4) {
            const float w0 = fwt[(4 * k4 + 0) * D_FUSE + d];
            const float w1 = fwt[(4 * k4 + 1) * D_FUSE + d];
            const float w2 = fwt[(4 * k4 + 2) * D_FUSE + d];
            const float w3 = fwt[(4 * k4 + 3) * D_FUSE + d];
            #pragma unroll
            for (int i = 0; i < 16; ++i) {
                const float4 xv = *(const float4*)&svin[sl0 + 2 * i][4 * k4];
                acc[i] = fmaf(xv.x, w0, fmaf(xv.y, w1, fmaf(xv.z, w2, fmaf(xv.w, w3, acc[i]))));
            }
        }
        for (int k = 64; k < D_CAT; ++k) {
            const float wv = fwt[k * D_FUSE + d];
            #pragma unroll
            for (int i = 0; i < 16; ++i)
                acc[i] = fmaf(svin[sl0 + 2 * i][k], wv, acc[i]);
        }
        #pragma unroll
        for (int i = 0; i < 16; ++i) svp[sl0 + 2 * i][d] = acc[i];
    }
    __syncthreads();

    for (int sl = 0; sl < SCHUNK; ++sl) {
        const float4* sv4 = (const float4*)(&svp[sl][dsl * 16]);
        float part = 0.f;
        #pragma unroll
        for (int j = 0; j < 4; ++j) {
            const float4 v = sv4[j];
            part = fmaf(fmaxf(v.x + lc[4*j+0], 0.f), wdr[4*j+0], part);
            part = fmaf(fmaxf(v.y + lc[4*j+1], 0.f), wdr[4*j+1], part);
            part = fmaf(fmaxf(v.z + lc[4*j+2], 0.f), wdr[4*j+2], part);
            part = fmaf(fmaxf(v.w + lc[4*j+3], 0.f), wdr[4*j+3], part);
        }
        part += __shfl_xor(part, 1);
        part += __shfl_xor(part, 2);
        part += __shfl_xor(part, 4);
        if (dsl == 0) score[sl][q] = sigmoidf_(part + hbd);
    }
    __syncthreads();

    for (int i = 0; i < 8; ++i) {
        const int cell = tid + 256 * i;            // q*64+g
        const int qq = cell >> 6, g = cell & 63;
        float sum = 0.f;
        #pragma unroll
        for (int sl = 0; sl < SCHUNK; ++sl)
            sum += (grps_l[sl] == g) ? score[sl][qq] : 0.f;
        grp_part[blockIdx.x * (Q_TOT * G_TOT) + cell] = sum;
        if (cell < G_TOT) {
            int c = 0;
            #pragma unroll
            for (int sl = 0; sl < SCHUNK; ++sl) c += (grps_l[sl] == g);
            cnt_part[blockIdx.x * G_TOT + g] = c;
        }
    }
}

// ---------------------------------------------------------------- two-stage reduction + argmax + smask
__global__ __launch_bounds__(256) void k_post(const float* __restrict__ grp_part,
                                              const int* __restrict__ cnt_part,
                                              const int* __restrict__ grps,
                                              float* __restrict__ grp2,
                                              int* __restrict__ cnt2,
                                              int* __restrict__ best,
                                              int* __restrict__ smask,
                                              int* __restrict__ qtick,
                                              int* __restrict__ gtick) {
    __shared__ float ps[4][G_TOT];
    __shared__ int   pc[4][G_TOT];
    __shared__ float sc[G_TOT];
    __shared__ int bl[Q_TOT];
    __shared__ int myturn, lastq;
    const int tid = threadIdx.x;
    const int q = blockIdx.x & 31, c = blockIdx.x >> 5;
    const int bq = tid >> 6, g = tid & 63;
    const int b0 = c * PTILES;
    int b1 = b0 + PTILES; if (b1 > NBLK3) b1 = NBLK3;

    float acc = 0.f; int cacc = 0;
    for (int b = b0 + bq; b < b1; b += 4) {
        acc  += grp_part[b * (Q_TOT * G_TOT) + q * G_TOT + g];
        cacc += cnt_part[b * G_TOT + g];
    }
    ps[bq][g] = acc; pc[bq][g] = cacc;
    __syncthreads();
    if (tid < G_TOT) {
        const float s = ((ps[0][tid] + ps[1][tid]) + ps[2][tid]) + ps[3][tid];
        const int  cc = ((pc[0][tid] + pc[1][tid]) + pc[2][tid]) + pc[3][tid];
        __hip_atomic_store(&grp2[(c * Q_TOT + q) * G_TOT + tid], s,
                           __ATOMIC_RELAXED, __HIP_MEMORY_SCOPE_AGENT);
        __hip_atomic_store(&cnt2[(c * Q_TOT + q) * G_TOT + tid], cc,
                           __ATOMIC_RELAXED, __HIP_MEMORY_SCOPE_AGENT);
    }
    asm volatile("s_waitcnt vmcnt(0)" ::: "memory");
    if (tid == 0) {
        const int old = __hip_atomic_fetch_add(&qtick[q], 1, __ATOMIC_RELAXED, __HIP_MEMORY_SCOPE_AGENT);
        myturn = (old == PCHUNK - 1) ? 1 : 0;
    }
    __syncthreads();
    if (!myturn) return;

    if (tid < G_TOT) {
        float s = 0.f; int cc = 0;
        #pragma unroll
        for (int c2 = 0; c2 < PCHUNK; ++c2) {
            s  += __hip_atomic_load(&grp2[(c2 * Q_TOT + q) * G_TOT + tid],
                                    __ATOMIC_RELAXED, __HIP_MEMORY_SCOPE_AGENT);
            cc += __hip_atomic_load(&cnt2[(c2 * Q_TOT + q) * G_TOT + tid],
                                    __ATOMIC_RELAXED, __HIP_MEMORY_SCOPE_AGENT);
        }
        sc[tid] = s / (float)cc;
    }
    __syncthreads();
    if (tid == 0) {
        float bv = sc[0]; int bi = 0;
        for (int g2 = 1; g2 < G_TOT; ++g2) if (sc[g2] > bv) { bv = sc[g2]; bi = g2; }
        __hip_atomic_store(&best[q], bi, __ATOMIC_RELAXED, __HIP_MEMORY_SCOPE_AGENT);
        asm volatile("s_waitcnt vmcnt(0)" ::: "memory");
        const int old = __hip_atomic_fetch_add(gtick, 1, __ATOMIC_RELAXED, __HIP_MEMORY_SCOPE_AGENT);
        lastq = (old == Q_TOT - 1) ? 1 : 0;
    }
    __syncthreads();
    if (!lastq) return;
    if (tid < Q_TOT) bl[tid] = __hip_atomic_load(&best[tid], __ATOMIC_RELAXED, __HIP_MEMORY_SCOPE_AGENT);
    __syncthreads();
    for (int s = tid; s < S_TOT; s += 256) {
        const int gg = grps[s];
        int m = 0;
        #pragma unroll
        for (int qq = 0; qq < Q_TOT; ++qq) m |= (bl[qq] == gg) ? (1 << qq) : 0;
        smask[s] = m;
    }
}

// ---------------------------------------------------------------- obj_pts + inter/union + iou (vectorized)
__global__ __launch_bounds__(256) void k_out(const int* __restrict__ supervox,
                                             const int* __restrict__ gt,
                                             const int* __restrict__ smask,
                                             float* __restrict__ out,
                                             int* __restrict__ interG, int* __restrict__ unionG,
                                             int* __restrict__ ticket) {
    const int tid = threadIdx.x;
    const int gidx = blockIdx.x * 256 + tid;
    const int q4 = (gidx & 7) * 4;
    const int nstride = (OUT_GRID * 256) >> 3;   // 65536
    int a0 = 0, a1 = 0, a2 = 0, a3 = 0;
    int u0 = 0, u1 = 0, u2 = 0, u3 = 0;
    for (int n = gidx >> 3; n < N_TOT; n += nstride) {
        const int m = smask[supervox[n]];
        const int4 g4 = *(const int4*)&gt[n * Q_TOT + q4];
        const int o0 = (m >> (q4 + 0)) & 1;
        const int o1 = (m >> (q4 + 1)) & 1;
        const int o2 = (m >> (q4 + 2)) & 1;
        const int o3 = (m >> (q4 + 3)) & 1;
        *(float4*)&out[n * Q_TOT + q4] =
            make_float4((float)o0, (float)o1, (float)o2, (float)o3);
        a0 += o0 & g4.x; u0 += o0 | g4.x;
        a1 += o1 & g4.y; u1 += o1 | g4.y;
        a2 += o2 & g4.z; u2 += o2 | g4.z;
        a3 += o3 & g4.w; u3 += o3 | g4.w;
    }
    __shared__ int bi[Q_TOT], bu[Q_TOT];
    __shared__ int islast;
    if (tid < Q_TOT) { bi[tid] = 0; bu[tid] = 0; }
    __syncthreads();
    atomicAdd(&bi[q4 + 0], a0); atomicAdd(&bu[q4 + 0], u0);
    atomicAdd(&bi[q4 + 1], a1); atomicAdd(&bu[q4 + 1], u1);
    atomicAdd(&bi[q4 + 2], a2); atomicAdd(&bu[q4 + 2], u2);
    atomicAdd(&bi[q4 + 3], a3); atomicAdd(&bu[q4 + 3], u3);
    __syncthreads();
    if (tid < Q_TOT) { atomicAdd(&interG[tid], bi[tid]); atomicAdd(&unionG[tid], bu[tid]); }
    asm volatile("s_waitcnt vmcnt(0)" ::: "memory");
    if (tid == 0) {
        const int old = __hip_atomic_fetch_add(ticket, 1, __ATOMIC_RELAXED, __HIP_MEMORY_SCOPE_AGENT);
        islast = (old == OUT_GRID - 1) ? 1 : 0;
    }
    __syncthreads();
    if (islast && tid < Q_TOT) {
        const int iv = __hip_atomic_load(&interG[tid], __ATOMIC_RELAXED, __HIP_MEMORY_SCOPE_AGENT);
        const int uv = __hip_atomic_load(&unionG[tid], __ATOMIC_RELAXED, __HIP_MEMORY_SCOPE_AGENT);
        out[(size_t)N_TOT * Q_TOT + tid] = (float)iv / ((float)uv + 1e-5f);
    }
}

extern "C" void kernel_launch(void* const* d_in, const int* in_sizes, int n_in,
                              void* d_out, int out_size, void* d_ws, size_t ws_size,
                              hipStream_t stream) {
    const float* lang_feat = (const float*)d_in[0];
    const float* feat      = (const float*)d_in[1];
    const float* coords    = (const float*)d_in[2];
    const int*   lang_len  = (const int*)d_in[3];
    const int*   grps      = (const int*)d_in[4];
    const int*   supervox  = (const int*)d_in[5];
    const int*   gt        = (const int*)d_in[6];
    const float* w_ih      = (const float*)d_in[7];
    const float* w_hh      = (const float*)d_in[8];
    const float* b_ih      = (const float*)d_in[9];
    const float* b_hh      = (const float*)d_in[10];
    const float* sqz_w1    = (const float*)d_in[11];
    const float* sqz_b1    = (const float*)d_in[12];
    const float* sqz_w2    = (const float*)d_in[13];
    const float* sqz_b2    = (const float*)d_in[14];
    const float* fuse_w    = (const float*)d_in[15];
    const float* fuse_b    = (const float*)d_in[16];
    const float* heat_w    = (const float*)d_in[17];
    const float* heat_b    = (const float*)d_in[18];
    float* out = (float*)d_out;

    float* gi       = (float*)d_ws;                       // 737280
    float* hbuf     = gi + 737280;                        // 8192
    float* langc    = hbuf + 8192;                        // 4096
    float* grp_part = langc + 4096;                       // 1280000
    int*   cnt_part = (int*)(grp_part + NBLK3 * 2048);    // 40000
    int*   best     = cnt_part + NBLK3 * 64;              // 32
    int*   smask    = best + 32;                          // 20000
    int*   syncs    = smask + S_TOT;                      // SYNCS_N ints
    float* hg       = (float*)(syncs + SYNCS_N);          // 245760
    float* fwt      = hg + HG_ELEMS;                      // 16768
    float* w1t      = fwt + FW_LD * D_FUSE;               // 16384
    float* w2t      = w1t + H_DIM * D_LANG;               // 4096
    float* wdr      = w2t + D_LANG * D_LANG;              // 128
    float* grp2     = wdr + 128;                          // 32768
    int*   cnt2     = (int*)(grp2 + PCHUNK * Q_TOT * G_TOT); // 32768

    k_gi   <<<GI_GRID + 9, 128, 0, stream>>>(lang_feat, w_ih, b_ih, fuse_w, sqz_w1, sqz_w2, heat_w,
                                             gi, fwt, w1t, w2t, wdr, hg, syncs);
    k_gru8 <<<Q_TOT * 8, 384, 0, stream>>>(gi, w_hh, b_hh, lang_len, hg, hbuf,
                                           w1t, sqz_b1, w2t, sqz_b2, fwt, fuse_b, langc,
                                           syncs + 66);
    k_fuse <<<NBLK3, 256, 0, stream>>>(feat, coords, grps, langc, fwt, wdr, heat_b,
                                       grp_part, cnt_part);
    k_post <<<Q_TOT * PCHUNK, 256, 0, stream>>>(grp_part, cnt_part, grps, grp2, cnt2,
                                                best, smask, syncs + 98, syncs + 65);
    k_out  <<<OUT_GRID, 256, 0, stream>>>(supervox, gt, smask, out, syncs, syncs + 32, syncs + 64);
}

// Round 14
// 236.946 us; speedup vs baseline: 1.1599x; 1.0530x over previous
//
#include <hip/hip_runtime.h>
#include <hip/hip_bf16.h>
#include <math.h>

#define S_TOT 20000
#define Q_TOT 32
#define N_TOT 200000
#define T_MAX 30
#define G_TOT 64
#define D_IN 300
#define H_DIM 256
#define D_SV 64
#define D_LANG 64
#define D_FUSE 128
#define D_CAT 67
#define FW_LD 131
#define SCHUNK 32
#define NBLK3 (S_TOT / SCHUNK)   // 625
#define SENT64 0xFFFFFFFFFFFFFFFFull
#define PCHUNK 16
#define PTILES 40

// k_gi GEMM tiling
#define GI_MT 32
#define GI_NT 64
#define GI_KC 100
#define GI_NB 12
#define GI_GRID (30 * GI_NB)     // 360
#define HG_ELEMS (30 * Q_TOT * H_DIM)

// syncs ints: [0..31] interG | [32..63] unionG | [64] t_out | [65] gtick
// [66..97] qdone | [98..129] qtick | [130] t_fuse | [131] t_smask
#define SYNCS_N 160

__device__ __forceinline__ float sigmoidf_(float x) { return 1.0f / (1.0f + expf(-x)); }
__device__ __forceinline__ unsigned long long pack2(float a, float b) {
    return ((unsigned long long)__float_as_uint(b) << 32) | (unsigned long long)__float_as_uint(a);
}
__device__ __forceinline__ void tick_wait(int* c, int tgt) {
    __syncthreads();
    if (threadIdx.x == 0) {
        while (__hip_atomic_load(c, __ATOMIC_RELAXED, __HIP_MEMORY_SCOPE_AGENT) < tgt)
            __builtin_amdgcn_s_sleep(4);
    }
    __syncthreads();
}
__device__ __forceinline__ void tick_bump(int* c) {
    asm volatile("s_waitcnt vmcnt(0)" ::: "memory");
    if (threadIdx.x == 0)
        __hip_atomic_fetch_add(c, 1, __ATOMIC_RELAXED, __HIP_MEMORY_SCOPE_AGENT);
}

// ---------------------------------------------------------------- k_gi
__global__ __launch_bounds__(128) void k_gi(const float* __restrict__ lang_feat,
                                            const float* __restrict__ w_ih,
                                            const float* __restrict__ b_ih,
                                            const float* __restrict__ fuse_w,
                                            const float* __restrict__ sqz_w1,
                                            const float* __restrict__ sqz_w2,
                                            const float* __restrict__ heat_w,
                                            float* __restrict__ gi,
                                            float* __restrict__ fwt,
                                            float* __restrict__ w1t,
                                            float* __restrict__ w2t,
                                            float* __restrict__ wdr,
                                            float* __restrict__ hg,
                                            int* __restrict__ syncs) {
    const int tid = threadIdx.x;
    if (blockIdx.x >= GI_GRID) {
        const int xb = blockIdx.x - GI_GRID;
        if (xb == 0) {
            for (int i = tid; i < FW_LD * D_FUSE; i += 128)
                fwt[(i % FW_LD) * D_FUSE + (i / FW_LD)] = fuse_w[i];
            for (int i = tid; i < D_LANG * H_DIM; i += 128)
                w1t[(i & 255) * D_LANG + (i >> 8)] = sqz_w1[i];
            for (int i = tid; i < D_LANG * D_LANG; i += 128)
                w2t[(i & 63) * D_LANG + (i >> 6)] = sqz_w2[i];
            if (tid < D_FUSE) wdr[tid] = heat_w[D_FUSE + tid] - heat_w[tid];
        } else {
            const int fb = xb - 1;                        // 0..7
            const int per4 = HG_ELEMS / 4 / 8;
            float4* dst = (float4*)hg + fb * per4;
            const float4 sv = make_float4(__uint_as_float(0xFFFFFFFFu), __uint_as_float(0xFFFFFFFFu),
                                          __uint_as_float(0xFFFFFFFFu), __uint_as_float(0xFFFFFFFFu));
            for (int i = tid; i < per4; i += 128) dst[i] = sv;
            if (fb == 0) for (int i = tid; i < SYNCS_N; i += 128) syncs[i] = 0;
        }
        return;
    }
    __shared__ float x_l[GI_KC][GI_MT + 1];
    __shared__ float w_l[GI_KC][GI_NT + 1];
    const int mb = blockIdx.x / GI_NB, nb = blockIdx.x % GI_NB;
    const int m0 = mb * GI_MT, n0 = nb * GI_NT;
    const int tq4 = (tid >> 4) * 4, jq4 = (tid & 15) * 4;

    float acc[4][4];
    #pragma unroll
    for (int i = 0; i < 4; ++i)
        #pragma unroll
        for (int j = 0; j < 4; ++j) acc[i][j] = 0.f;

    for (int kc = 0; kc < 3; ++kc) {
        const int k0 = kc * GI_KC;
        for (int i = tid; i < GI_MT * GI_KC; i += 128) {
            const int r = i / GI_KC, k = i % GI_KC;
            const int row = m0 + r, q = row / T_MAX, t = row - q * T_MAX;
            x_l[k][r] = lang_feat[(q * T_MAX + t) * D_IN + k0 + k];
        }
        for (int i = tid; i < GI_NT * GI_KC; i += 128) {
            const int r = i / GI_KC, k = i % GI_KC;
            w_l[k][r] = w_ih[(n0 + r) * D_IN + k0 + k];
        }
        __syncthreads();
        #pragma unroll 2
        for (int k = 0; k < GI_KC; ++k) {
            const float x0 = x_l[k][tq4 + 0], x1 = x_l[k][tq4 + 1];
            const float x2 = x_l[k][tq4 + 2], x3 = x_l[k][tq4 + 3];
            const float v0 = w_l[k][jq4 + 0], v1 = w_l[k][jq4 + 1];
            const float v2 = w_l[k][jq4 + 2], v3 = w_l[k][jq4 + 3];
            acc[0][0] = fmaf(x0, v0, acc[0][0]); acc[0][1] = fmaf(x0, v1, acc[0][1]);
            acc[0][2] = fmaf(x0, v2, acc[0][2]); acc[0][3] = fmaf(x0, v3, acc[0][3]);
            acc[1][0] = fmaf(x1, v0, acc[1][0]); acc[1][1] = fmaf(x1, v1, acc[1][1]);
            acc[1][2] = fmaf(x1, v2, acc[1][2]); acc[1][3] = fmaf(x1, v3, acc[1][3]);
            acc[2][0] = fmaf(x2, v0, acc[2][0]); acc[2][1] = fmaf(x2, v1, acc[2][1]);
            acc[2][2] = fmaf(x2, v2, acc[2][2]); acc[2][3] = fmaf(x2, v3, acc[2][3]);
            acc[3][0] = fmaf(x3, v0, acc[3][0]); acc[3][1] = fmaf(x3, v1, acc[3][1]);
            acc[3][2] = fmaf(x3, v2, acc[3][2]); acc[3][3] = fmaf(x3, v3, acc[3][3]);
        }
        __syncthreads();
    }
    const float b0 = b_ih[n0 + jq4 + 0], b1 = b_ih[n0 + jq4 + 1];
    const float b2 = b_ih[n0 + jq4 + 2], b3 = b_ih[n0 + jq4 + 3];
    #pragma unroll
    for (int i = 0; i < 4; ++i) {
        const int row = m0 + tq4 + i;
        const int q = row / T_MAX, t = row - q * T_MAX;
        float4 v = make_float4(acc[i][0] + b0, acc[i][1] + b1, acc[i][2] + b2, acc[i][3] + b3);
        *(float4*)&gi[(q * T_MAX + t) * 768 + n0 + jq4] = v;
    }
}

// ---------------------------------------------------------------- cooperative GRU + lang fold (R13)
__global__ __launch_bounds__(384, 1) void k_gru8(const float* __restrict__ gi,
                                                 const float* __restrict__ w_hh,
                                                 const float* __restrict__ b_hh,
                                                 const int* __restrict__ lang_len,
                                                 float* __restrict__ hg,
                                                 float* __restrict__ hbuf,
                                                 const float* __restrict__ w1t,
                                                 const float* __restrict__ b1,
                                                 const float* __restrict__ w2t,
                                                 const float* __restrict__ b2,
                                                 const float* __restrict__ fwt,
                                                 const float* __restrict__ fuse_b,
                                                 float* __restrict__ langc,
                                                 int* __restrict__ qdone) {
    __shared__ __align__(16) float wlds[96 * 256];
    __shared__ __align__(16) float hlq[4 * 68];
    __shared__ float ghl[96];
    __shared__ float gil[T_MAX * 96];

    const int tid = threadIdx.x;
    const int q = blockIdx.x >> 3, b = blockIdx.x & 7;
    int len = lang_len[q]; if (len > T_MAX) len = T_MAX; if (len < 1) len = 1;

    {
        const float4* src4 = (const float4*)w_hh;
        float4* dst4 = (float4*)wlds;
        for (int i = tid; i < 96 * 64; i += 384) {
            const int r = i >> 6, c = i & 63;
            const int grow = ((r >> 5) << 8) + (b << 5) + (r & 31);
            dst4[r * 64 + (c ^ (r & 7))] = src4[grow * 64 + c];
        }
    }
    for (int i = tid; i < len * 96; i += 384) {
        const int t = i / 96, r = i % 96;
        gil[i] = gi[(q * T_MAX + t) * 768 + ((r >> 5) << 8) + (b << 5) + (r & 31)];
    }
    __syncthreads();

    float hfin = 0.f;
    {
        float hnew = 0.f;
        if (tid < 32) {
            const float bhr = b_hh[(b << 5) + tid];
            const float bhz = b_hh[H_DIM + (b << 5) + tid];
            const float bhn = b_hh[2 * H_DIM + (b << 5) + tid];
            const float r = sigmoidf_(gil[tid] + bhr);
            const float z = sigmoidf_(gil[32 + tid] + bhz);
            const float n = tanhf(gil[64 + tid] + r * bhn);
            hnew = (1.f - z) * n;
            if (len == 1) hfin = hnew;
        }
        if (tid < 64 && len > 1) {
            const float a0 = __shfl(hnew, 2 * (tid & 15));
            const float a1 = __shfl(hnew, 2 * (tid & 15) + 1);
            if (tid < 16) {
                unsigned long long* dst = (unsigned long long*)(hg + q * H_DIM + (b << 5));
                __hip_atomic_store(dst + tid, pack2(a0, a1), __ATOMIC_RELAXED, __HIP_MEMORY_SCOPE_AGENT);
            }
        }
    }

    const int row = tid >> 2, ql = tid & 3;
    const float bh = b_hh[((row >> 5) << 8) + (b << 5) + (row & 31)];
    const int rx = row & 7;
    const float4* wrow4 = (const float4*)wlds + row * 64;
    const int cbase = ql << 4;

    for (int t = 1; t < len; ++t) {
        if (tid < 128) {
            const unsigned long long* src =
                (const unsigned long long*)(hg + (size_t)(t - 1) * (Q_TOT * H_DIM) + q * H_DIM);
            unsigned long long v;
            while ((v = __hip_atomic_load(src + tid, __ATOMIC_RELAXED,
                                          __HIP_MEMORY_SCOPE_AGENT)) == SENT64)
                __builtin_amdgcn_s_sleep(1);
            const int k = 2 * tid;
            const int o = (k >> 6) * 68 + (k & 63);
            hlq[o]     = __uint_as_float((unsigned)(v & 0xffffffffu));
            hlq[o + 1] = __uint_as_float((unsigned)(v >> 32));
        }
        __syncthreads();
        float hold = 0.f;
        if (tid < 32) { const int k = (b << 5) + tid; hold = hlq[(k >> 6) * 68 + (k & 63)]; }
        const float4* h4 = (const float4*)(hlq + ql * 68);
        float ax = 0.f, ay = 0.f, az = 0.f, aw = 0.f;
        #pragma unroll
        for (int i = 0; i < 16; ++i) {
            const float4 wv = wrow4[(cbase + i) ^ rx];
            const float4 hv = h4[i];
            ax = fmaf(wv.x, hv.x, ax);
            ay = fmaf(wv.y, hv.y, ay);
            az = fmaf(wv.z, hv.z, az);
            aw = fmaf(wv.w, hv.w, aw);
        }
        float s = (ax + ay) + (az + aw);
        s += __shfl_xor(s, 1);
        s += __shfl_xor(s, 2);
        if (ql == 0) ghl[row] = s + bh;
        __syncthreads();
        float hnew = 0.f;
        if (tid < 32) {
            const float* gt_ = gil + t * 96;
            const float r = sigmoidf_(gt_[tid] + ghl[tid]);
            const float z = sigmoidf_(gt_[32 + tid] + ghl[32 + tid]);
            const float n = tanhf(gt_[64 + tid] + r * ghl[64 + tid]);
            hnew = (1.f - z) * n + z * hold;
            if (t == len - 1) hfin = hnew;
        }
        if (tid < 64 && t < len - 1) {
            const float a0 = __shfl(hnew, 2 * (tid & 15));
            const float a1 = __shfl(hnew, 2 * (tid & 15) + 1);
            if (tid < 16) {
                unsigned long long* dst =
                    (unsigned long long*)(hg + (size_t)t * (Q_TOT * H_DIM) + q * H_DIM + (b << 5));
                __hip_atomic_store(dst + tid, pack2(a0, a1), __ATOMIC_RELAXED, __HIP_MEMORY_SCOPE_AGENT);
            }
        }
    }

    if (tid < 32)
        __hip_atomic_store(&hbuf[q * H_DIM + (b << 5) + tid], hfin,
                           __ATOMIC_RELAXED, __HIP_MEMORY_SCOPE_AGENT);
    asm volatile("s_waitcnt vmcnt(0)" ::: "memory");
    __syncthreads();
    if (tid == 0)
        __hip_atomic_fetch_add(&qdone[q], 1, __ATOMIC_RELAXED, __HIP_MEMORY_SCOPE_AGENT);
    if (b != 0) return;

    if (tid == 0) {
        while (__hip_atomic_load(&qdone[q], __ATOMIC_RELAXED, __HIP_MEMORY_SCOPE_AGENT) < 8)
            __builtin_amdgcn_s_sleep(2);
    }
    __syncthreads();
    float* hql = gil;
    float* t1l = gil + 256;
    float* lgl = gil + 320;
    if (tid < H_DIM)
        hql[tid] = __hip_atomic_load(&hbuf[q * H_DIM + tid], __ATOMIC_RELAXED, __HIP_MEMORY_SCOPE_AGENT);
    __syncthreads();
    if (tid < 256) {
        const int c = tid >> 2, qq = tid & 3;
        float a = 0.f;
        #pragma unroll 8
        for (int j = 0; j < 64; ++j) {
            const int k = (qq << 6) + j;
            a = fmaf(w1t[k * D_LANG + c], hql[k], a);
        }
        a += __shfl_xor(a, 1);
        a += __shfl_xor(a, 2);
        if (qq == 0) t1l[c] = fmaxf(a + b1[c], 0.f);
    }
    __syncthreads();
    if (tid < 256) {
        const int c = tid >> 2, qq = tid & 3;
        float a = 0.f;
        #pragma unroll
        for (int j = 0; j < 16; ++j) {
            const int k = (qq << 4) + j;
            a = fmaf(w2t[k * D_LANG + c], t1l[k], a);
        }
        a += __shfl_xor(a, 1);
        a += __shfl_xor(a, 2);
        if (qq == 0) lgl[c] = a + b2[c];
    }
    __syncthreads();
    if (tid < 256) {
        const int d = tid >> 1, hh = tid & 1;
        float a = 0.f;
        #pragma unroll 8
        for (int j = 0; j < 32; ++j) {
            const int k = (hh << 5) + j;
            a = fmaf(fwt[(D_CAT + k) * D_FUSE + d], lgl[k], a);
        }
        a += __shfl_xor(a, 1);
        if (hh == 0) langc[q * D_FUSE + d] = a + fuse_b[d];
    }
}

// ---------------------------------------------------------------- k_tail: fuse | reduce+argmax | smask | out | iou
// 625 blocks, all co-resident (34 KB LDS -> 4/CU capacity). Cross-phase data via agent
// (LLC) stores/loads; phase handoff via tickets (vmcnt-drained producer, relaxed bump).
__global__ __launch_bounds__(256, 3) void k_tail(const float* __restrict__ feat,
                                                 const float* __restrict__ coords,
                                                 const int* __restrict__ grps,
                                                 const float* __restrict__ langc,
                                                 const float* __restrict__ fwt,
                                                 const float* __restrict__ wdr_g,
                                                 const float* __restrict__ heat_b,
                                                 float* __restrict__ grp_part,
                                                 int* __restrict__ cnt_part,
                                                 float* __restrict__ grp2,
                                                 int* __restrict__ cnt2,
                                                 int* __restrict__ best,
                                                 int* __restrict__ smask,
                                                 const int* __restrict__ supervox,
                                                 const int* __restrict__ gt,
                                                 float* __restrict__ out,
                                                 int* __restrict__ syncs) {
    int* interG   = syncs;
    int* unionG   = syncs + 32;
    int* t_out    = syncs + 64;
    int* gtick    = syncs + 65;
    int* qtick    = syncs + 98;
    int* t_fuse   = syncs + 130;
    int* t_smask  = syncs + 131;
    const int tid = threadIdx.x;
    const int bid = blockIdx.x;

    __shared__ __align__(16) float svin[SCHUNK][68];
    __shared__ __align__(16) float svp[SCHUNK][132];
    __shared__ float score[SCHUNK][Q_TOT];
    __shared__ int grps_l[SCHUNK];
    __shared__ float ps[4][G_TOT];
    __shared__ int   pc[4][G_TOT];
    __shared__ float sc[G_TOT];
    __shared__ int bl[Q_TOT];
    __shared__ int bi_s[Q_TOT], bu_s[Q_TOT];
    __shared__ int islast;

    // ================= phase F: fused sv_proj + score + partials (1 tile per block)
    {
        const int s0 = bid * SCHUNK;
        const int dsl = tid & 7, q = tid >> 3;
        float lc[16], wdr[16];
        #pragma unroll
        for (int i = 0; i < 16; ++i) {
            const int d = dsl * 16 + i;
            lc[i]  = langc[q * D_FUSE + d];
            wdr[i] = wdr_g[d];
        }
        const float hbd = heat_b[1] - heat_b[0];

        for (int i = tid; i < SCHUNK * D_SV; i += 256) {
            const int r = i >> 6, c = i & 63;
            svin[r][c] = feat[(s0 + r) * D_SV + c];
        }
        if (tid < SCHUNK * 3) { const int r = tid / 3, c = tid % 3; svin[r][D_SV + c] = coords[(s0 + r) * 3 + c]; }
        if (tid < SCHUNK) grps_l[tid] = grps[s0 + tid];
        __syncthreads();

        {
            const int d = tid & 127, sl0 = tid >> 7;
            float acc[16];
            #pragma unroll
            for (int i = 0; i < 16; ++i) acc[i] = 0.f;
            for (int k4 = 0; k4 < 16; ++k4) {
                const float w0 = fwt[(4 * k4 + 0) * D_FUSE + d];
                const float w1 = fwt[(4 * k4 + 1) * D_FUSE + d];
                const float w2 = fwt[(4 * k4 + 2) * D_FUSE + d];
                const float w3 = fwt[(4 * k4 + 3) * D_FUSE + d];
                #pragma unroll
                for (int i = 0; i < 16; ++i) {
                    const float4 xv = *(const float4*)&svin[sl0 + 2 * i][4 * k4];
                    acc[i] = fmaf(xv.x, w0, fmaf(xv.y, w1, fmaf(xv.z, w2, fmaf(xv.w, w3, acc[i]))));
                }
            }
            for (int k = 64; k < D_CAT; ++k) {
                const float wv = fwt[k * D_FUSE + d];
                #pragma unroll
                for (int i = 0; i < 16; ++i)
                    acc[i] = fmaf(svin[sl0 + 2 * i][k], wv, acc[i]);
            }
            #pragma unroll
            for (int i = 0; i < 16; ++i) svp[sl0 + 2 * i][d] = acc[i];
        }
        __syncthreads();

        for (int sl = 0; sl < SCHUNK; ++sl) {
            const float4* sv4 = (const float4*)(&svp[sl][dsl * 16]);
            float part = 0.f;
            #pragma unroll
            for (int j = 0; j < 4; ++j) {
                const float4 v = sv4[j];
                part = fmaf(fmaxf(v.x + lc[4*j+0], 0.f), wdr[4*j+0], part);
                part = fmaf(fmaxf(v.y + lc[4*j+1], 0.f), wdr[4*j+1], part);
                part = fmaf(fmaxf(v.z + lc[4*j+2], 0.f), wdr[4*j+2], part);
                part = fmaf(fmaxf(v.w + lc[4*j+3], 0.f), wdr[4*j+3], part);
            }
            part += __shfl_xor(part, 1);
            part += __shfl_xor(part, 2);
            part += __shfl_xor(part, 4);
            if (dsl == 0) score[sl][q] = sigmoidf_(part + hbd);
        }
        __syncthreads();

        for (int i = 0; i < 8; ++i) {
            const int cell = tid + 256 * i;
            const int qq = cell >> 6, g = cell & 63;
            float sum = 0.f;
            #pragma unroll
            for (int sl = 0; sl < SCHUNK; ++sl)
                sum += (grps_l[sl] == g) ? score[sl][qq] : 0.f;
            __hip_atomic_store(&grp_part[bid * (Q_TOT * G_TOT) + cell], sum,
                               __ATOMIC_RELAXED, __HIP_MEMORY_SCOPE_AGENT);
            if (cell < G_TOT) {
                int c = 0;
                #pragma unroll
                for (int sl = 0; sl < SCHUNK; ++sl) c += (grps_l[sl] == g);
                __hip_atomic_store(&cnt_part[bid * G_TOT + g], c,
                                   __ATOMIC_RELAXED, __HIP_MEMORY_SCOPE_AGENT);
            }
        }
        tick_bump(t_fuse);
    }
    tick_wait(t_fuse, NBLK3);

    // ================= phase A: two-stage reduction + argmax (blocks 0..511)
    if (bid < Q_TOT * PCHUNK) {
        const int q = bid & 31, c = bid >> 5;
        const int bq = tid >> 6, g = tid & 63;
        const int b0 = c * PTILES;
        int b1 = b0 + PTILES; if (b1 > NBLK3) b1 = NBLK3;
        float acc = 0.f; int cacc = 0;
        for (int b = b0 + bq; b < b1; b += 4) {
            acc  += __hip_atomic_load(&grp_part[b * (Q_TOT * G_TOT) + q * G_TOT + g],
                                      __ATOMIC_RELAXED, __HIP_MEMORY_SCOPE_AGENT);
            cacc += __hip_atomic_load(&cnt_part[b * G_TOT + g],
                                      __ATOMIC_RELAXED, __HIP_MEMORY_SCOPE_AGENT);
        }
        ps[bq][g] = acc; pc[bq][g] = cacc;
        __syncthreads();
        if (tid < G_TOT) {
            const float s = ((ps[0][tid] + ps[1][tid]) + ps[2][tid]) + ps[3][tid];
            const int  cc = ((pc[0][tid] + pc[1][tid]) + pc[2][tid]) + pc[3][tid];
            __hip_atomic_store(&grp2[(c * Q_TOT + q) * G_TOT + tid], s,
                               __ATOMIC_RELAXED, __HIP_MEMORY_SCOPE_AGENT);
            __hip_atomic_store(&cnt2[(c * Q_TOT + q) * G_TOT + tid], cc,
                               __ATOMIC_RELAXED, __HIP_MEMORY_SCOPE_AGENT);
        }
        __shared__ int myturn;
        asm volatile("s_waitcnt vmcnt(0)" ::: "memory");
        if (tid == 0) {
            const int old = __hip_atomic_fetch_add(&qtick[q], 1, __ATOMIC_RELAXED, __HIP_MEMORY_SCOPE_AGENT);
            myturn = (old == PCHUNK - 1) ? 1 : 0;
        }
        __syncthreads();
        if (myturn) {
            if (tid < G_TOT) {
                float s = 0.f; int cc = 0;
                #pragma unroll
                for (int c2 = 0; c2 < PCHUNK; ++c2) {
                    s  += __hip_atomic_load(&grp2[(c2 * Q_TOT + q) * G_TOT + tid],
                                            __ATOMIC_RELAXED, __HIP_MEMORY_SCOPE_AGENT);
                    cc += __hip_atomic_load(&cnt2[(c2 * Q_TOT + q) * G_TOT + tid],
                                            __ATOMIC_RELAXED, __HIP_MEMORY_SCOPE_AGENT);
                }
                sc[tid] = s / (float)cc;
            }
            __syncthreads();
            if (tid == 0) {
                float bv = sc[0]; int bi = 0;
                for (int g2 = 1; g2 < G_TOT; ++g2) if (sc[g2] > bv) { bv = sc[g2]; bi = g2; }
                __hip_atomic_store(&best[q], bi, __ATOMIC_RELAXED, __HIP_MEMORY_SCOPE_AGENT);
                asm volatile("s_waitcnt vmcnt(0)" ::: "memory");
                __hip_atomic_fetch_add(gtick, 1, __ATOMIC_RELAXED, __HIP_MEMORY_SCOPE_AGENT);
            }
        }
    }
    tick_wait(gtick, Q_TOT);

    // ================= phase S: smask (block bid owns rows bid*32..bid*32+32)
    if (tid < Q_TOT) bl[tid] = __hip_atomic_load(&best[tid], __ATOMIC_RELAXED, __HIP_MEMORY_SCOPE_AGENT);
    __syncthreads();
    if (tid < 32) {
        const int s = bid * 32 + tid;
        const int gg = grps[s];
        int m = 0;
        #pragma unroll
        for (int qq = 0; qq < Q_TOT; ++qq) m |= (bl[qq] == gg) ? (1 << qq) : 0;
        __hip_atomic_store(&smask[s], m, __ATOMIC_RELAXED, __HIP_MEMORY_SCOPE_AGENT);
    }
    tick_bump(t_smask);
    tick_wait(t_smask, NBLK3);

    // ================= phase O: obj_pts + inter/union + iou
    {
        const int gidx = bid * 256 + tid;          // 160000 threads
        const int q4 = (gidx & 7) * 4;
        const int nstride = (NBLK3 * 256) >> 3;    // 20000
        int a0 = 0, a1 = 0, a2 = 0, a3 = 0;
        int u0 = 0, u1 = 0, u2 = 0, u3 = 0;
        for (int n = gidx >> 3; n < N_TOT; n += nstride) {
            const int m = __hip_atomic_load(&smask[supervox[n]],
                                            __ATOMIC_RELAXED, __HIP_MEMORY_SCOPE_AGENT);
            const int4 g4 = *(const int4*)&gt[n * Q_TOT + q4];
            const int o0 = (m >> (q4 + 0)) & 1;
            const int o1 = (m >> (q4 + 1)) & 1;
            const int o2 = (m >> (q4 + 2)) & 1;
            const int o3 = (m >> (q4 + 3)) & 1;
            *(float4*)&out[n * Q_TOT + q4] =
                make_float4((float)o0, (float)o1, (float)o2, (float)o3);
            a0 += o0 & g4.x; u0 += o0 | g4.x;
            a1 += o1 & g4.y; u1 += o1 | g4.y;
            a2 += o2 & g4.z; u2 += o2 | g4.z;
            a3 += o3 & g4.w; u3 += o3 | g4.w;
        }
        if (tid < Q_TOT) { bi_s[tid] = 0; bu_s[tid] = 0; }
        __syncthreads();
        atomicAdd(&bi_s[q4 + 0], a0); atomicAdd(&bu_s[q4 + 0], u0);
        atomicAdd(&bi_s[q4 + 1], a1); atomicAdd(&bu_s[q4 + 1], u1);
        atomicAdd(&bi_s[q4 + 2], a2); atomicAdd(&bu_s[q4 + 2], u2);
        atomicAdd(&bi_s[q4 + 3], a3); atomicAdd(&bu_s[q4 + 3], u3);
        __syncthreads();
        if (tid < Q_TOT) { atomicAdd(&interG[tid], bi_s[tid]); atomicAdd(&unionG[tid], bu_s[tid]); }
        asm volatile("s_waitcnt vmcnt(0)" ::: "memory");
        if (tid == 0) {
            const int old = __hip_atomic_fetch_add(t_out, 1, __ATOMIC_RELAXED, __HIP_MEMORY_SCOPE_AGENT);
            islast = (old == NBLK3 - 1) ? 1 : 0;
        }
        __syncthreads();
        if (islast && tid < Q_TOT) {
            const int iv = __hip_atomic_load(&interG[tid], __ATOMIC_RELAXED, __HIP_MEMORY_SCOPE_AGENT);
            const int uv = __hip_atomic_load(&unionG[tid], __ATOMIC_RELAXED, __HIP_MEMORY_SCOPE_AGENT);
            out[(size_t)N_TOT * Q_TOT + tid] = (float)iv / ((float)uv + 1e-5f);
        }
    }
}

extern "C" void kernel_launch(void* const* d_in, const int* in_sizes, int n_in,
                              void* d_out, int out_size, void* d_ws, size_t ws_size,
                              hipStream_t stream) {
    const float* lang_feat = (const float*)d_in[0];
    const float* feat      = (const float*)d_in[1];
    const float* coords    = (const float*)d_in[2];
    const int*   lang_len  = (const int*)d_in[3];
    const int*   grps      = (const int*)d_in[4];
    const int*   supervox  = (const int*)d_in[5];
    const int*   gt        = (const int*)d_in[6];
    const float* w_ih      = (const float*)d_in[7];
    const float* w_hh      = (const float*)d_in[8];
    const float* b_ih      = (const float*)d_in[9];
    const float* b_hh      = (const float*)d_in[10];
    const float* sqz_w1    = (const float*)d_in[11];
    const float* sqz_b1    = (const float*)d_in[12];
    const float* sqz_w2    = (const float*)d_in[13];
    const float* sqz_b2    = (const float*)d_in[14];
    const float* fuse_w    = (const float*)d_in[15];
    const float* fuse_b    = (const float*)d_in[16];
    const float* heat_w    = (const float*)d_in[17];
    const float* heat_b    = (const float*)d_in[18];
    float* out = (float*)d_out;

    float* gi       = (float*)d_ws;                       // 737280
    float* hbuf     = gi + 737280;                        // 8192
    float* langc    = hbuf + 8192;                        // 4096
    float* grp_part = langc + 4096;                       // 1280000
    int*   cnt_part = (int*)(grp_part + NBLK3 * 2048);    // 40000
    int*   best     = cnt_part + NBLK3 * 64;              // 32
    int*   smask    = best + 32;                          // 20000
    int*   syncs    = smask + S_TOT;                      // SYNCS_N
    float* hg       = (float*)(syncs + SYNCS_N);          // 245760
    float* fwt      = hg + HG_ELEMS;                      // 16768
    float* w1t      = fwt + FW_LD * D_FUSE;               // 16384
    float* w2t      = w1t + H_DIM * D_LANG;               // 4096
    float* wdr      = w2t + D_LANG * D_LANG;              // 128
    float* grp2     = wdr + 128;                          // 32768
    int*   cnt2     = (int*)(grp2 + PCHUNK * Q_TOT * G_TOT); // 32768

    k_gi   <<<GI_GRID + 9, 128, 0, stream>>>(lang_feat, w_ih, b_ih, fuse_w, sqz_w1, sqz_w2, heat_w,
                                             gi, fwt, w1t, w2t, wdr, hg, syncs);
    k_gru8 <<<Q_TOT * 8, 384, 0, stream>>>(gi, w_hh, b_hh, lang_len, hg, hbuf,
                                           w1t, sqz_b1, w2t, sqz_b2, fwt, fuse_b, langc,
                                           syncs + 66);
    k_tail <<<NBLK3, 256, 0, stream>>>(feat, coords, grps, langc, fwt, wdr, heat_b,
                                       grp_part, cnt_part, grp2, cnt2, best, smask,
                                       supervox, gt, out, syncs);
}

// Round 15
// 234.188 us; speedup vs baseline: 1.1736x; 1.0118x over previous
//
#include <hip/hip_runtime.h>
#include <hip/hip_bf16.h>
#include <math.h>

#define S_TOT 20000
#define Q_TOT 32
#define N_TOT 200000
#define T_MAX 30
#define G_TOT 64
#define D_IN 300
#define H_DIM 256
#define D_SV 64
#define D_LANG 64
#define D_FUSE 128
#define D_CAT 67
#define FW_LD 131
#define SCHUNK 32
#define NBLK3 (S_TOT / SCHUNK)   // 625
#define SENT64 0xFFFFFFFFFFFFFFFFull
#define PCHUNK 16
#define PTILES 40

// k_gi GEMM tiling
#define GI_MT 32
#define GI_NT 64
#define GI_KC 100
#define GI_NB 12
#define GI_GRID (30 * GI_NB)     // 360
#define HG_ELEMS (30 * Q_TOT * H_DIM)

// syncs ints: [0..31] interG | [32..63] unionG | [64] t_out | [65] gtick
// [66..97] qdone | [98..129] qtick | [130] t_fuse | [131] t_smask
#define SYNCS_N 160

__device__ __forceinline__ float sigmoidf_(float x) { return 1.0f / (1.0f + expf(-x)); }
__device__ __forceinline__ unsigned long long pack2(float a, float b) {
    return ((unsigned long long)__float_as_uint(b) << 32) | (unsigned long long)__float_as_uint(a);
}
__device__ __forceinline__ void tick_wait(int* c, int tgt) {
    __syncthreads();
    if (threadIdx.x == 0) {
        while (__hip_atomic_load(c, __ATOMIC_RELAXED, __HIP_MEMORY_SCOPE_AGENT) < tgt)
            __builtin_amdgcn_s_sleep(4);
    }
    __syncthreads();
}
__device__ __forceinline__ void tick_bump(int* c) {
    asm volatile("s_waitcnt vmcnt(0)" ::: "memory");
    if (threadIdx.x == 0)
        __hip_atomic_fetch_add(c, 1, __ATOMIC_RELAXED, __HIP_MEMORY_SCOPE_AGENT);
}

// ---------------------------------------------------------------- k_gi
__global__ __launch_bounds__(128) void k_gi(const float* __restrict__ lang_feat,
                                            const float* __restrict__ w_ih,
                                            const float* __restrict__ b_ih,
                                            const float* __restrict__ fuse_w,
                                            const float* __restrict__ sqz_w1,
                                            const float* __restrict__ sqz_w2,
                                            const float* __restrict__ heat_w,
                                            float* __restrict__ gi,
                                            float* __restrict__ fwt,
                                            float* __restrict__ w1t,
                                            float* __restrict__ w2t,
                                            float* __restrict__ wdr,
                                            float* __restrict__ hg,
                                            int* __restrict__ syncs) {
    const int tid = threadIdx.x;
    if (blockIdx.x >= GI_GRID) {
        const int xb = blockIdx.x - GI_GRID;
        if (xb == 0) {
            for (int i = tid; i < FW_LD * D_FUSE; i += 128)
                fwt[(i % FW_LD) * D_FUSE + (i / FW_LD)] = fuse_w[i];
            for (int i = tid; i < D_LANG * H_DIM; i += 128)
                w1t[(i & 255) * D_LANG + (i >> 8)] = sqz_w1[i];
            for (int i = tid; i < D_LANG * D_LANG; i += 128)
                w2t[(i & 63) * D_LANG + (i >> 6)] = sqz_w2[i];
            if (tid < D_FUSE) wdr[tid] = heat_w[D_FUSE + tid] - heat_w[tid];
        } else {
            const int fb = xb - 1;                        // 0..7
            const int per4 = HG_ELEMS / 4 / 8;
            float4* dst = (float4*)hg + fb * per4;
            const float4 sv = make_float4(__uint_as_float(0xFFFFFFFFu), __uint_as_float(0xFFFFFFFFu),
                                          __uint_as_float(0xFFFFFFFFu), __uint_as_float(0xFFFFFFFFu));
            for (int i = tid; i < per4; i += 128) dst[i] = sv;
            if (fb == 0) for (int i = tid; i < SYNCS_N; i += 128) syncs[i] = 0;
        }
        return;
    }
    __shared__ float x_l[GI_KC][GI_MT + 1];
    __shared__ float w_l[GI_KC][GI_NT + 1];
    const int mb = blockIdx.x / GI_NB, nb = blockIdx.x % GI_NB;
    const int m0 = mb * GI_MT, n0 = nb * GI_NT;
    const int tq4 = (tid >> 4) * 4, jq4 = (tid & 15) * 4;

    float acc[4][4];
    #pragma unroll
    for (int i = 0; i < 4; ++i)
        #pragma unroll
        for (int j = 0; j < 4; ++j) acc[i][j] = 0.f;

    for (int kc = 0; kc < 3; ++kc) {
        const int k0 = kc * GI_KC;
        for (int i = tid; i < GI_MT * GI_KC; i += 128) {
            const int r = i / GI_KC, k = i % GI_KC;
            const int row = m0 + r, q = row / T_MAX, t = row - q * T_MAX;
            x_l[k][r] = lang_feat[(q * T_MAX + t) * D_IN + k0 + k];
        }
        for (int i = tid; i < GI_NT * GI_KC; i += 128) {
            const int r = i / GI_KC, k = i % GI_KC;
            w_l[k][r] = w_ih[(n0 + r) * D_IN + k0 + k];
        }
        __syncthreads();
        #pragma unroll 2
        for (int k = 0; k < GI_KC; ++k) {
            const float x0 = x_l[k][tq4 + 0], x1 = x_l[k][tq4 + 1];
            const float x2 = x_l[k][tq4 + 2], x3 = x_l[k][tq4 + 3];
            const float v0 = w_l[k][jq4 + 0], v1 = w_l[k][jq4 + 1];
            const float v2 = w_l[k][jq4 + 2], v3 = w_l[k][jq4 + 3];
            acc[0][0] = fmaf(x0, v0, acc[0][0]); acc[0][1] = fmaf(x0, v1, acc[0][1]);
            acc[0][2] = fmaf(x0, v2, acc[0][2]); acc[0][3] = fmaf(x0, v3, acc[0][3]);
            acc[1][0] = fmaf(x1, v0, acc[1][0]); acc[1][1] = fmaf(x1, v1, acc[1][1]);
            acc[1][2] = fmaf(x1, v2, acc[1][2]); acc[1][3] = fmaf(x1, v3, acc[1][3]);
            acc[2][0] = fmaf(x2, v0, acc[2][0]); acc[2][1] = fmaf(x2, v1, acc[2][1]);
            acc[2][2] = fmaf(x2, v2, acc[2][2]); acc[2][3] = fmaf(x2, v3, acc[2][3]);
            acc[3][0] = fmaf(x3, v0, acc[3][0]); acc[3][1] = fmaf(x3, v1, acc[3][1]);
            acc[3][2] = fmaf(x3, v2, acc[3][2]); acc[3][3] = fmaf(x3, v3, acc[3][3]);
        }
        __syncthreads();
    }
    const float b0 = b_ih[n0 + jq4 + 0], b1 = b_ih[n0 + jq4 + 1];
    const float b2 = b_ih[n0 + jq4 + 2], b3 = b_ih[n0 + jq4 + 3];
    #pragma unroll
    for (int i = 0; i < 4; ++i) {
        const int row = m0 + tq4 + i;
        const int q = row / T_MAX, t = row - q * T_MAX;
        float4 v = make_float4(acc[i][0] + b0, acc[i][1] + b1, acc[i][2] + b2, acc[i][3] + b3);
        *(float4*)&gi[(q * T_MAX + t) * 768 + n0 + jq4] = v;
    }
}

// ---------------------------------------------------------------- cooperative GRU + lang fold
__global__ __launch_bounds__(384, 1) void k_gru8(const float* __restrict__ gi,
                                                 const float* __restrict__ w_hh,
                                                 const float* __restrict__ b_hh,
                                                 const int* __restrict__ lang_len,
                                                 float* __restrict__ hg,
                                                 float* __restrict__ hbuf,
                                                 const float* __restrict__ w1t,
                                                 const float* __restrict__ b1,
                                                 const float* __restrict__ w2t,
                                                 const float* __restrict__ b2,
                                                 const float* __restrict__ fwt,
                                                 const float* __restrict__ fuse_b,
                                                 float* __restrict__ langc,
                                                 int* __restrict__ qdone) {
    __shared__ __align__(16) float wlds[96 * 256];
    __shared__ __align__(16) float hlq[4 * 68];
    __shared__ float ghl[96];
    __shared__ float gil[T_MAX * 96];

    const int tid = threadIdx.x;
    const int q = blockIdx.x >> 3, b = blockIdx.x & 7;
    int len = lang_len[q]; if (len > T_MAX) len = T_MAX; if (len < 1) len = 1;

    {
        const float4* src4 = (const float4*)w_hh;
        float4* dst4 = (float4*)wlds;
        for (int i = tid; i < 96 * 64; i += 384) {
            const int r = i >> 6, c = i & 63;
            const int grow = ((r >> 5) << 8) + (b << 5) + (r & 31);
            dst4[r * 64 + (c ^ (r & 7))] = src4[grow * 64 + c];
        }
    }
    for (int i = tid; i < len * 96; i += 384) {
        const int t = i / 96, r = i % 96;
        gil[i] = gi[(q * T_MAX + t) * 768 + ((r >> 5) << 8) + (b << 5) + (r & 31)];
    }
    __syncthreads();

    float hfin = 0.f;
    {
        float hnew = 0.f;
        if (tid < 32) {
            const float bhr = b_hh[(b << 5) + tid];
            const float bhz = b_hh[H_DIM + (b << 5) + tid];
            const float bhn = b_hh[2 * H_DIM + (b << 5) + tid];
            const float r = sigmoidf_(gil[tid] + bhr);
            const float z = sigmoidf_(gil[32 + tid] + bhz);
            const float n = tanhf(gil[64 + tid] + r * bhn);
            hnew = (1.f - z) * n;
            if (len == 1) hfin = hnew;
        }
        if (tid < 64 && len > 1) {
            const float a0 = __shfl(hnew, 2 * (tid & 15));
            const float a1 = __shfl(hnew, 2 * (tid & 15) + 1);
            if (tid < 16) {
                unsigned long long* dst = (unsigned long long*)(hg + q * H_DIM + (b << 5));
                __hip_atomic_store(dst + tid, pack2(a0, a1), __ATOMIC_RELAXED, __HIP_MEMORY_SCOPE_AGENT);
            }
        }
    }

    const int row = tid >> 2, ql = tid & 3;
    const float bh = b_hh[((row >> 5) << 8) + (b << 5) + (row & 31)];
    const int rx = row & 7;
    const float4* wrow4 = (const float4*)wlds + row * 64;
    const int cbase = ql << 4;

    for (int t = 1; t < len; ++t) {
        if (tid < 128) {
            const unsigned long long* src =
                (const unsigned long long*)(hg + (size_t)(t - 1) * (Q_TOT * H_DIM) + q * H_DIM);
            unsigned long long v;
            while ((v = __hip_atomic_load(src + tid, __ATOMIC_RELAXED,
                                          __HIP_MEMORY_SCOPE_AGENT)) == SENT64)
                __builtin_amdgcn_s_sleep(1);
            const int k = 2 * tid;
            const int o = (k >> 6) * 68 + (k & 63);
            hlq[o]     = __uint_as_float((unsigned)(v & 0xffffffffu));
            hlq[o + 1] = __uint_as_float((unsigned)(v >> 32));
        }
        __syncthreads();
        float hold = 0.f;
        if (tid < 32) { const int k = (b << 5) + tid; hold = hlq[(k >> 6) * 68 + (k & 63)]; }
        const float4* h4 = (const float4*)(hlq + ql * 68);
        float ax = 0.f, ay = 0.f, az = 0.f, aw = 0.f;
        #pragma unroll
        for (int i = 0; i < 16; ++i) {
            const float4 wv = wrow4[(cbase + i) ^ rx];
            const float4 hv = h4[i];
            ax = fmaf(wv.x, hv.x, ax);
            ay = fmaf(wv.y, hv.y, ay);
            az = fmaf(wv.z, hv.z, az);
            aw = fmaf(wv.w, hv.w, aw);
        }
        float s = (ax + ay) + (az + aw);
        s += __shfl_xor(s, 1);
        s += __shfl_xor(s, 2);
        if (ql == 0) ghl[row] = s + bh;
        __syncthreads();
        float hnew = 0.f;
        if (tid < 32) {
            const float* gt_ = gil + t * 96;
            const float r = sigmoidf_(gt_[tid] + ghl[tid]);
            const float z = sigmoidf_(gt_[32 + tid] + ghl[32 + tid]);
            const float n = tanhf(gt_[64 + tid] + r * ghl[64 + tid]);
            hnew = (1.f - z) * n + z * hold;
            if (t == len - 1) hfin = hnew;
        }
        if (tid < 64 && t < len - 1) {
            const float a0 = __shfl(hnew, 2 * (tid & 15));
            const float a1 = __shfl(hnew, 2 * (tid & 15) + 1);
            if (tid < 16) {
                unsigned long long* dst =
                    (unsigned long long*)(hg + (size_t)t * (Q_TOT * H_DIM) + q * H_DIM + (b << 5));
                __hip_atomic_store(dst + tid, pack2(a0, a1), __ATOMIC_RELAXED, __HIP_MEMORY_SCOPE_AGENT);
            }
        }
    }

    if (tid < 32)
        __hip_atomic_store(&hbuf[q * H_DIM + (b << 5) + tid], hfin,
                           __ATOMIC_RELAXED, __HIP_MEMORY_SCOPE_AGENT);
    asm volatile("s_waitcnt vmcnt(0)" ::: "memory");
    __syncthreads();
    if (tid == 0)
        __hip_atomic_fetch_add(&qdone[q], 1, __ATOMIC_RELAXED, __HIP_MEMORY_SCOPE_AGENT);
    if (b != 0) return;

    if (tid == 0) {
        while (__hip_atomic_load(&qdone[q], __ATOMIC_RELAXED, __HIP_MEMORY_SCOPE_AGENT) < 8)
            __builtin_amdgcn_s_sleep(2);
    }
    __syncthreads();
    float* hql = gil;
    float* t1l = gil + 256;
    float* lgl = gil + 320;
    if (tid < H_DIM)
        hql[tid] = __hip_atomic_load(&hbuf[q * H_DIM + tid], __ATOMIC_RELAXED, __HIP_MEMORY_SCOPE_AGENT);
    __syncthreads();
    if (tid < 256) {
        const int c = tid >> 2, qq = tid & 3;
        float a = 0.f;
        #pragma unroll 8
        for (int j = 0; j < 64; ++j) {
            const int k = (qq << 6) + j;
            a = fmaf(w1t[k * D_LANG + c], hql[k], a);
        }
        a += __shfl_xor(a, 1);
        a += __shfl_xor(a, 2);
        if (qq == 0) t1l[c] = fmaxf(a + b1[c], 0.f);
    }
    __syncthreads();
    if (tid < 256) {
        const int c = tid >> 2, qq = tid & 3;
        float a = 0.f;
        #pragma unroll
        for (int j = 0; j < 16; ++j) {
            const int k = (qq << 4) + j;
            a = fmaf(w2t[k * D_LANG + c], t1l[k], a);
        }
        a += __shfl_xor(a, 1);
        a += __shfl_xor(a, 2);
        if (qq == 0) lgl[c] = a + b2[c];
    }
    __syncthreads();
    if (tid < 256) {
        const int d = tid >> 1, hh = tid & 1;
        float a = 0.f;
        #pragma unroll 8
        for (int j = 0; j < 32; ++j) {
            const int k = (hh << 5) + j;
            a = fmaf(fwt[(D_CAT + k) * D_FUSE + d], lgl[k], a);
        }
        a += __shfl_xor(a, 1);
        if (hh == 0) langc[q * D_FUSE + d] = a + fuse_b[d];
    }
}

// ---------------------------------------------------------------- k_tail: fuse | reduce+argmax | smask | out | iou
// Cross-phase WRITES: agent-scope stores (LLC-visible before ticket bump).
// Cross-phase READS (after barrier): PLAIN cached loads — safe: every region is
// first-touched by the reading XCD after the write (L2s invalid at kernel start,
// no pre-barrier reads of these regions), so no stale L2 lines can exist.
__global__ __launch_bounds__(256, 3) void k_tail(const float* __restrict__ feat,
                                                 const float* __restrict__ coords,
                                                 const int* __restrict__ grps,
                                                 const float* __restrict__ langc,
                                                 const float* __restrict__ fwt,
                                                 const float* __restrict__ wdr_g,
                                                 const float* __restrict__ heat_b,
                                                 float* __restrict__ grp_part,
                                                 int* __restrict__ cnt_part,
                                                 float* __restrict__ grp2,
                                                 int* __restrict__ cnt2,
                                                 int* __restrict__ best,
                                                 int* __restrict__ smask,
                                                 const int* __restrict__ supervox,
                                                 const int* __restrict__ gt,
                                                 float* __restrict__ out,
                                                 int* __restrict__ syncs) {
    int* interG   = syncs;
    int* unionG   = syncs + 32;
    int* t_out    = syncs + 64;
    int* gtick    = syncs + 65;
    int* qtick    = syncs + 98;
    int* t_fuse   = syncs + 130;
    int* t_smask  = syncs + 131;
    const int tid = threadIdx.x;
    const int bid = blockIdx.x;

    __shared__ __align__(16) float svin[SCHUNK][68];
    __shared__ __align__(16) float svp[SCHUNK][132];
    __shared__ float score[SCHUNK][Q_TOT];
    __shared__ int grps_l[SCHUNK];
    __shared__ float ps[4][G_TOT];
    __shared__ int   pc[4][G_TOT];
    __shared__ float sc[G_TOT];
    __shared__ int bl[Q_TOT];
    __shared__ int bi_s[Q_TOT], bu_s[Q_TOT];
    __shared__ int islast;

    // ================= phase F
    {
        const int s0 = bid * SCHUNK;
        const int dsl = tid & 7, q = tid >> 3;
        float lc[16], wdr[16];
        #pragma unroll
        for (int i = 0; i < 16; ++i) {
            const int d = dsl * 16 + i;
            lc[i]  = langc[q * D_FUSE + d];
            wdr[i] = wdr_g[d];
        }
        const float hbd = heat_b[1] - heat_b[0];

        for (int i = tid; i < SCHUNK * D_SV; i += 256) {
            const int r = i >> 6, c = i & 63;
            svin[r][c] = feat[(s0 + r) * D_SV + c];
        }
        if (tid < SCHUNK * 3) { const int r = tid / 3, c = tid % 3; svin[r][D_SV + c] = coords[(s0 + r) * 3 + c]; }
        if (tid < SCHUNK) grps_l[tid] = grps[s0 + tid];
        __syncthreads();

        {
            const int d = tid & 127, sl0 = tid >> 7;
            float acc[16];
            #pragma unroll
            for (int i = 0; i < 16; ++i) acc[i] = 0.f;
            for (int k4 = 0; k4 < 16; ++k4) {
                const float w0 = fwt[(4 * k4 + 0) * D_FUSE + d];
                const float w1 = fwt[(4 * k4 + 1) * D_FUSE + d];
                const float w2 = fwt[(4 * k4 + 2) * D_FUSE + d];
                const float w3 = fwt[(4 * k4 + 3) * D_FUSE + d];
                #pragma unroll
                for (int i = 0; i < 16; ++i) {
                    const float4 xv = *(const float4*)&svin[sl0 + 2 * i][4 * k4];
                    acc[i] = fmaf(xv.x, w0, fmaf(xv.y, w1, fmaf(xv.z, w2, fmaf(xv.w, w3, acc[i]))));
                }
            }
            for (int k = 64; k < D_CAT; ++k) {
                const float wv = fwt[k * D_FUSE + d];
                #pragma unroll
                for (int i = 0; i < 16; ++i)
                    acc[i] = fmaf(svin[sl0 + 2 * i][k], wv, acc[i]);
            }
            #pragma unroll
            for (int i = 0; i < 16; ++i) svp[sl0 + 2 * i][d] = acc[i];
        }
        __syncthreads();

        for (int sl = 0; sl < SCHUNK; ++sl) {
            const float4* sv4 = (const float4*)(&svp[sl][dsl * 16]);
            float part = 0.f;
            #pragma unroll
            for (int j = 0; j < 4; ++j) {
                const float4 v = sv4[j];
                part = fmaf(fmaxf(v.x + lc[4*j+0], 0.f), wdr[4*j+0], part);
                part = fmaf(fmaxf(v.y + lc[4*j+1], 0.f), wdr[4*j+1], part);
                part = fmaf(fmaxf(v.z + lc[4*j+2], 0.f), wdr[4*j+2], part);
                part = fmaf(fmaxf(v.w + lc[4*j+3], 0.f), wdr[4*j+3], part);
            }
            part += __shfl_xor(part, 1);
            part += __shfl_xor(part, 2);
            part += __shfl_xor(part, 4);
            if (dsl == 0) score[sl][q] = sigmoidf_(part + hbd);
        }
        __syncthreads();

        for (int i = 0; i < 8; ++i) {
            const int cell = tid + 256 * i;
            const int qq = cell >> 6, g = cell & 63;
            float sum = 0.f;
            #pragma unroll
            for (int sl = 0; sl < SCHUNK; ++sl)
                sum += (grps_l[sl] == g) ? score[sl][qq] : 0.f;
            __hip_atomic_store(&grp_part[bid * (Q_TOT * G_TOT) + cell], sum,
                               __ATOMIC_RELAXED, __HIP_MEMORY_SCOPE_AGENT);
            if (cell < G_TOT) {
                int c = 0;
                #pragma unroll
                for (int sl = 0; sl < SCHUNK; ++sl) c += (grps_l[sl] == g);
                __hip_atomic_store(&cnt_part[bid * G_TOT + g], c,
                                   __ATOMIC_RELAXED, __HIP_MEMORY_SCOPE_AGENT);
            }
        }
        tick_bump(t_fuse);
    }
    tick_wait(t_fuse, NBLK3);

    // ================= phase A (plain cached reads)
    if (bid < Q_TOT * PCHUNK) {
        const int q = bid & 31, c = bid >> 5;
        const int bq = tid >> 6, g = tid & 63;
        const int b0 = c * PTILES;
        int b1 = b0 + PTILES; if (b1 > NBLK3) b1 = NBLK3;
        float acc = 0.f; int cacc = 0;
        for (int b = b0 + bq; b < b1; b += 4) {
            acc  += grp_part[b * (Q_TOT * G_TOT) + q * G_TOT + g];
            cacc += cnt_part[b * G_TOT + g];
        }
        ps[bq][g] = acc; pc[bq][g] = cacc;
        __syncthreads();
        if (tid < G_TOT) {
            const float s = ((ps[0][tid] + ps[1][tid]) + ps[2][tid]) + ps[3][tid];
            const int  cc = ((pc[0][tid] + pc[1][tid]) + pc[2][tid]) + pc[3][tid];
            __hip_atomic_store(&grp2[(c * Q_TOT + q) * G_TOT + tid], s,
                               __ATOMIC_RELAXED, __HIP_MEMORY_SCOPE_AGENT);
            __hip_atomic_store(&cnt2[(c * Q_TOT + q) * G_TOT + tid], cc,
                               __ATOMIC_RELAXED, __HIP_MEMORY_SCOPE_AGENT);
        }
        __shared__ int myturn;
        asm volatile("s_waitcnt vmcnt(0)" ::: "memory");
        if (tid == 0) {
            const int old = __hip_atomic_fetch_add(&qtick[q], 1, __ATOMIC_RELAXED, __HIP_MEMORY_SCOPE_AGENT);
            myturn = (old == PCHUNK - 1) ? 1 : 0;
        }
        __syncthreads();
        if (myturn) {
            if (tid < G_TOT) {
                float s = 0.f; int cc = 0;
                #pragma unroll
                for (int c2 = 0; c2 < PCHUNK; ++c2) {
                    s  += grp2[(c2 * Q_TOT + q) * G_TOT + tid];
                    cc += cnt2[(c2 * Q_TOT + q) * G_TOT + tid];
                }
                sc[tid] = s / (float)cc;
            }
            __syncthreads();
            if (tid == 0) {
                float bv = sc[0]; int bi = 0;
                for (int g2 = 1; g2 < G_TOT; ++g2) if (sc[g2] > bv) { bv = sc[g2]; bi = g2; }
                __hip_atomic_store(&best[q], bi, __ATOMIC_RELAXED, __HIP_MEMORY_SCOPE_AGENT);
                asm volatile("s_waitcnt vmcnt(0)" ::: "memory");
                __hip_atomic_fetch_add(gtick, 1, __ATOMIC_RELAXED, __HIP_MEMORY_SCOPE_AGENT);
            }
        }
    }
    tick_wait(gtick, Q_TOT);

    // ================= phase S (plain read of best)
    if (tid < Q_TOT) bl[tid] = best[tid];
    __syncthreads();
    if (tid < 32) {
        const int s = bid * 32 + tid;
        const int gg = grps[s];
        int m = 0;
        #pragma unroll
        for (int qq = 0; qq < Q_TOT; ++qq) m |= (bl[qq] == gg) ? (1 << qq) : 0;
        __hip_atomic_store(&smask[s], m, __ATOMIC_RELAXED, __HIP_MEMORY_SCOPE_AGENT);
    }
    tick_bump(t_smask);
    tick_wait(t_smask, NBLK3);

    // ================= phase O (plain cached smask reads)
    {
        const int gidx = bid * 256 + tid;
        const int q4 = (gidx & 7) * 4;
        const int nstride = (NBLK3 * 256) >> 3;    // 20000
        int a0 = 0, a1 = 0, a2 = 0, a3 = 0;
        int u0 = 0, u1 = 0, u2 = 0, u3 = 0;
        for (int n = gidx >> 3; n < N_TOT; n += nstride) {
            const int m = smask[supervox[n]];
            const int4 g4 = *(const int4*)&gt[n * Q_TOT + q4];
            const int o0 = (m >> (q4 + 0)) & 1;
            const int o1 = (m >> (q4 + 1)) & 1;
            const int o2 = (m >> (q4 + 2)) & 1;
            const int o3 = (m >> (q4 + 3)) & 1;
            *(float4*)&out[n * Q_TOT + q4] =
                make_float4((float)o0, (float)o1, (float)o2, (float)o3);
            a0 += o0 & g4.x; u0 += o0 | g4.x;
            a1 += o1 & g4.y; u1 += o1 | g4.y;
            a2 += o2 & g4.z; u2 += o2 | g4.z;
            a3 += o3 & g4.w; u3 += o3 | g4.w;
        }
        if (tid < Q_TOT) { bi_s[tid] = 0; bu_s[tid] = 0; }
        __syncthreads();
        atomicAdd(&bi_s[q4 + 0], a0); atomicAdd(&bu_s[q4 + 0], u0);
        atomicAdd(&bi_s[q4 + 1], a1); atomicAdd(&bu_s[q4 + 1], u1);
        atomicAdd(&bi_s[q4 + 2], a2); atomicAdd(&bu_s[q4 + 2], u2);
        atomicAdd(&bi_s[q4 + 3], a3); atomicAdd(&bu_s[q4 + 3], u3);
        __syncthreads();
        if (tid < Q_TOT) { atomicAdd(&interG[tid], bi_s[tid]); atomicAdd(&unionG[tid], bu_s[tid]); }
        asm volatile("s_waitcnt vmcnt(0)" ::: "memory");
        if (tid == 0) {
            const int old = __hip_atomic_fetch_add(t_out, 1, __ATOMIC_RELAXED, __HIP_MEMORY_SCOPE_AGENT);
            islast = (old == NBLK3 - 1) ? 1 : 0;
        }
        __syncthreads();
        if (islast && tid < Q_TOT) {
            const int iv = __hip_atomic_load(&interG[tid], __ATOMIC_RELAXED, __HIP_MEMORY_SCOPE_AGENT);
            const int uv = __hip_atomic_load(&unionG[tid], __ATOMIC_RELAXED, __HIP_MEMORY_SCOPE_AGENT);
            out[(size_t)N_TOT * Q_TOT + tid] = (float)iv / ((float)uv + 1e-5f);
        }
    }
}

extern "C" void kernel_launch(void* const* d_in, const int* in_sizes, int n_in,
                              void* d_out, int out_size, void* d_ws, size_t ws_size,
                              hipStream_t stream) {
    const float* lang_feat = (const float*)d_in[0];
    const float* feat      = (const float*)d_in[1];
    const float* coords    = (const float*)d_in[2];
    const int*   lang_len  = (const int*)d_in[3];
    const int*   grps      = (const int*)d_in[4];
    const int*   supervox  = (const int*)d_in[5];
    const int*   gt        = (const int*)d_in[6];
    const float* w_ih      = (const float*)d_in[7];
    const float* w_hh      = (const float*)d_in[8];
    const float* b_ih      = (const float*)d_in[9];
    const float* b_hh      = (const float*)d_in[10];
    const float* sqz_w1    = (const float*)d_in[11];
    const float* sqz_b1    = (const float*)d_in[12];
    const float* sqz_w2    = (const float*)d_in[13];
    const float* sqz_b2    = (const float*)d_in[14];
    const float* fuse_w    = (const float*)d_in[15];
    const float* fuse_b    = (const float*)d_in[16];
    const float* heat_w    = (const float*)d_in[17];
    const float* heat_b    = (const float*)d_in[18];
    float* out = (float*)d_out;

    float* gi       = (float*)d_ws;                       // 737280
    float* hbuf     = gi + 737280;                        // 8192
    float* langc    = hbuf + 8192;                        // 4096
    float* grp_part = langc + 4096;                       // 1280000
    int*   cnt_part = (int*)(grp_part + NBLK3 * 2048);    // 40000
    int*   best     = cnt_part + NBLK3 * 64;              // 32
    int*   smask    = best + 32;                          // 20000
    int*   syncs    = smask + S_TOT;                      // SYNCS_N
    float* hg       = (float*)(syncs + SYNCS_N);          // 245760
    float* fwt      = hg + HG_ELEMS;                      // 16768
    float* w1t      = fwt + FW_LD * D_FUSE;               // 16384
    float* w2t      = w1t + H_DIM * D_LANG;               // 4096
    float* wdr      = w2t + D_LANG * D_LANG;              // 128
    float* grp2     = wdr + 128;                          // 32768
    int*   cnt2     = (int*)(grp2 + PCHUNK * Q_TOT * G_TOT); // 32768

    k_gi   <<<GI_GRID + 9, 128, 0, stream>>>(lang_feat, w_ih, b_ih, fuse_w, sqz_w1, sqz_w2, heat_w,
                                             gi, fwt, w1t, w2t, wdr, hg, syncs);
    k_gru8 <<<Q_TOT * 8, 384, 0, stream>>>(gi, w_hh, b_hh, lang_len, hg, hbuf,
                                           w1t, sqz_b1, w2t, sqz_b2, fwt, fuse_b, langc,
                                           syncs + 66);
    k_tail <<<NBLK3, 256, 0, stream>>>(feat, coords, grps, langc, fwt, wdr, heat_b,
                                       grp_part, cnt_part, grp2, cnt2, best, smask,
                                       supervox, gt, out, syncs);
}

// Round 16
// 200.594 us; speedup vs baseline: 1.3701x; 1.1675x over previous
//
#include <hip/hip_runtime.h>
#include <hip/hip_bf16.h>
#include <math.h>

#define S_TOT 20000
#define Q_TOT 32
#define N_TOT 200000
#define T_MAX 30
#define G_TOT 64
#define D_IN 300
#define H_DIM 256
#define D_SV 64
#define D_LANG 64
#define D_FUSE 128
#define D_CAT 67
#define FW_LD 131
#define SCHUNK 32
#define NBLK3 (S_TOT / SCHUNK)   // 625
#define SENT64 0xFFFFFFFFFFFFFFFFull
#define PCHUNK 16
#define PTILES 40

// k_gi GEMM tiling
#define GI_MT 32
#define GI_NT 64
#define GI_KC 100
#define GI_NB 12
#define GI_GRID (30 * GI_NB)     // 360
#define HG_ELEMS (30 * Q_TOT * H_DIM)

// syncs ints (line-spaced hot counters):
// [0..31] interG | [32..63] unionG | [64] t_out | [65] gtick
// [66..97] qdone (gru) | [98..129] qtick
// [160+32c] tfc chunk tickets (c=0..15) | [672+32i] doneflag (i=0..7)
#define SYNCS_N 1024

__device__ __forceinline__ float sigmoidf_(float x) { return 1.0f / (1.0f + expf(-x)); }
__device__ __forceinline__ unsigned long long pack2(float a, float b) {
    return ((unsigned long long)__float_as_uint(b) << 32) | (unsigned long long)__float_as_uint(a);
}

// ---------------------------------------------------------------- k_gi
__global__ __launch_bounds__(128) void k_gi(const float* __restrict__ lang_feat,
                                            const float* __restrict__ w_ih,
                                            const float* __restrict__ b_ih,
                                            const float* __restrict__ fuse_w,
                                            const float* __restrict__ sqz_w1,
                                            const float* __restrict__ sqz_w2,
                                            const float* __restrict__ heat_w,
                                            float* __restrict__ gi,
                                            float* __restrict__ fwt,
                                            float* __restrict__ w1t,
                                            float* __restrict__ w2t,
                                            float* __restrict__ wdr,
                                            float* __restrict__ hg,
                                            int* __restrict__ syncs) {
    const int tid = threadIdx.x;
    if (blockIdx.x >= GI_GRID) {
        const int xb = blockIdx.x - GI_GRID;
        if (xb == 0) {
            for (int i = tid; i < FW_LD * D_FUSE; i += 128)
                fwt[(i % FW_LD) * D_FUSE + (i / FW_LD)] = fuse_w[i];
            for (int i = tid; i < D_LANG * H_DIM; i += 128)
                w1t[(i & 255) * D_LANG + (i >> 8)] = sqz_w1[i];
            for (int i = tid; i < D_LANG * D_LANG; i += 128)
                w2t[(i & 63) * D_LANG + (i >> 6)] = sqz_w2[i];
            if (tid < D_FUSE) wdr[tid] = heat_w[D_FUSE + tid] - heat_w[tid];
        } else {
            const int fb = xb - 1;                        // 0..7
            const int per4 = HG_ELEMS / 4 / 8;
            float4* dst = (float4*)hg + fb * per4;
            const float4 sv = make_float4(__uint_as_float(0xFFFFFFFFu), __uint_as_float(0xFFFFFFFFu),
                                          __uint_as_float(0xFFFFFFFFu), __uint_as_float(0xFFFFFFFFu));
            for (int i = tid; i < per4; i += 128) dst[i] = sv;
            if (fb == 0) for (int i = tid; i < SYNCS_N; i += 128) syncs[i] = 0;
        }
        return;
    }
    __shared__ float x_l[GI_KC][GI_MT + 1];
    __shared__ float w_l[GI_KC][GI_NT + 1];
    const int mb = blockIdx.x / GI_NB, nb = blockIdx.x % GI_NB;
    const int m0 = mb * GI_MT, n0 = nb * GI_NT;
    const int tq4 = (tid >> 4) * 4, jq4 = (tid & 15) * 4;

    float acc[4][4];
    #pragma unroll
    for (int i = 0; i < 4; ++i)
        #pragma unroll
        for (int j = 0; j < 4; ++j) acc[i][j] = 0.f;

    for (int kc = 0; kc < 3; ++kc) {
        const int k0 = kc * GI_KC;
        for (int i = tid; i < GI_MT * GI_KC; i += 128) {
            const int r = i / GI_KC, k = i % GI_KC;
            const int row = m0 + r, q = row / T_MAX, t = row - q * T_MAX;
            x_l[k][r] = lang_feat[(q * T_MAX + t) * D_IN + k0 + k];
        }
        for (int i = tid; i < GI_NT * GI_KC; i += 128) {
            const int r = i / GI_KC, k = i % GI_KC;
            w_l[k][r] = w_ih[(n0 + r) * D_IN + k0 + k];
        }
        __syncthreads();
        #pragma unroll 2
        for (int k = 0; k < GI_KC; ++k) {
            const float x0 = x_l[k][tq4 + 0], x1 = x_l[k][tq4 + 1];
            const float x2 = x_l[k][tq4 + 2], x3 = x_l[k][tq4 + 3];
            const float v0 = w_l[k][jq4 + 0], v1 = w_l[k][jq4 + 1];
            const float v2 = w_l[k][jq4 + 2], v3 = w_l[k][jq4 + 3];
            acc[0][0] = fmaf(x0, v0, acc[0][0]); acc[0][1] = fmaf(x0, v1, acc[0][1]);
            acc[0][2] = fmaf(x0, v2, acc[0][2]); acc[0][3] = fmaf(x0, v3, acc[0][3]);
            acc[1][0] = fmaf(x1, v0, acc[1][0]); acc[1][1] = fmaf(x1, v1, acc[1][1]);
            acc[1][2] = fmaf(x1, v2, acc[1][2]); acc[1][3] = fmaf(x1, v3, acc[1][3]);
            acc[2][0] = fmaf(x2, v0, acc[2][0]); acc[2][1] = fmaf(x2, v1, acc[2][1]);
            acc[2][2] = fmaf(x2, v2, acc[2][2]); acc[2][3] = fmaf(x2, v3, acc[2][3]);
            acc[3][0] = fmaf(x3, v0, acc[3][0]); acc[3][1] = fmaf(x3, v1, acc[3][1]);
            acc[3][2] = fmaf(x3, v2, acc[3][2]); acc[3][3] = fmaf(x3, v3, acc[3][3]);
        }
        __syncthreads();
    }
    const float b0 = b_ih[n0 + jq4 + 0], b1 = b_ih[n0 + jq4 + 1];
    const float b2 = b_ih[n0 + jq4 + 2], b3 = b_ih[n0 + jq4 + 3];
    #pragma unroll
    for (int i = 0; i < 4; ++i) {
        const int row = m0 + tq4 + i;
        const int q = row / T_MAX, t = row - q * T_MAX;
        float4 v = make_float4(acc[i][0] + b0, acc[i][1] + b1, acc[i][2] + b2, acc[i][3] + b3);
        *(float4*)&gi[(q * T_MAX + t) * 768 + n0 + jq4] = v;
    }
}

// ---------------------------------------------------------------- cooperative GRU + lang fold (unchanged)
__global__ __launch_bounds__(384, 1) void k_gru8(const float* __restrict__ gi,
                                                 const float* __restrict__ w_hh,
                                                 const float* __restrict__ b_hh,
                                                 const int* __restrict__ lang_len,
                                                 float* __restrict__ hg,
                                                 float* __restrict__ hbuf,
                                                 const float* __restrict__ w1t,
                                                 const float* __restrict__ b1,
                                                 const float* __restrict__ w2t,
                                                 const float* __restrict__ b2,
                                                 const float* __restrict__ fwt,
                                                 const float* __restrict__ fuse_b,
                                                 float* __restrict__ langc,
                                                 int* __restrict__ qdone) {
    __shared__ __align__(16) float wlds[96 * 256];
    __shared__ __align__(16) float hlq[4 * 68];
    __shared__ float ghl[96];
    __shared__ float gil[T_MAX * 96];

    const int tid = threadIdx.x;
    const int q = blockIdx.x >> 3, b = blockIdx.x & 7;
    int len = lang_len[q]; if (len > T_MAX) len = T_MAX; if (len < 1) len = 1;

    {
        const float4* src4 = (const float4*)w_hh;
        float4* dst4 = (float4*)wlds;
        for (int i = tid; i < 96 * 64; i += 384) {
            const int r = i >> 6, c = i & 63;
            const int grow = ((r >> 5) << 8) + (b << 5) + (r & 31);
            dst4[r * 64 + (c ^ (r & 7))] = src4[grow * 64 + c];
        }
    }
    for (int i = tid; i < len * 96; i += 384) {
        const int t = i / 96, r = i % 96;
        gil[i] = gi[(q * T_MAX + t) * 768 + ((r >> 5) << 8) + (b << 5) + (r & 31)];
    }
    __syncthreads();

    float hfin = 0.f;
    {
        float hnew = 0.f;
        if (tid < 32) {
            const float bhr = b_hh[(b << 5) + tid];
            const float bhz = b_hh[H_DIM + (b << 5) + tid];
            const float bhn = b_hh[2 * H_DIM + (b << 5) + tid];
            const float r = sigmoidf_(gil[tid] + bhr);
            const float z = sigmoidf_(gil[32 + tid] + bhz);
            const float n = tanhf(gil[64 + tid] + r * bhn);
            hnew = (1.f - z) * n;
            if (len == 1) hfin = hnew;
        }
        if (tid < 64 && len > 1) {
            const float a0 = __shfl(hnew, 2 * (tid & 15));
            const float a1 = __shfl(hnew, 2 * (tid & 15) + 1);
            if (tid < 16) {
                unsigned long long* dst = (unsigned long long*)(hg + q * H_DIM + (b << 5));
                __hip_atomic_store(dst + tid, pack2(a0, a1), __ATOMIC_RELAXED, __HIP_MEMORY_SCOPE_AGENT);
            }
        }
    }

    const int row = tid >> 2, ql = tid & 3;
    const float bh = b_hh[((row >> 5) << 8) + (b << 5) + (row & 31)];
    const int rx = row & 7;
    const float4* wrow4 = (const float4*)wlds + row * 64;
    const int cbase = ql << 4;

    for (int t = 1; t < len; ++t) {
        if (tid < 128) {
            const unsigned long long* src =
                (const unsigned long long*)(hg + (size_t)(t - 1) * (Q_TOT * H_DIM) + q * H_DIM);
            unsigned long long v;
            while ((v = __hip_atomic_load(src + tid, __ATOMIC_RELAXED,
                                          __HIP_MEMORY_SCOPE_AGENT)) == SENT64)
                __builtin_amdgcn_s_sleep(1);
            const int k = 2 * tid;
            const int o = (k >> 6) * 68 + (k & 63);
            hlq[o]     = __uint_as_float((unsigned)(v & 0xffffffffu));
            hlq[o + 1] = __uint_as_float((unsigned)(v >> 32));
        }
        __syncthreads();
        float hold = 0.f;
        if (tid < 32) { const int k = (b << 5) + tid; hold = hlq[(k >> 6) * 68 + (k & 63)]; }
        const float4* h4 = (const float4*)(hlq + ql * 68);
        float ax = 0.f, ay = 0.f, az = 0.f, aw = 0.f;
        #pragma unroll
        for (int i = 0; i < 16; ++i) {
            const float4 wv = wrow4[(cbase + i) ^ rx];
            const float4 hv = h4[i];
            ax = fmaf(wv.x, hv.x, ax);
            ay = fmaf(wv.y, hv.y, ay);
            az = fmaf(wv.z, hv.z, az);
            aw = fmaf(wv.w, hv.w, aw);
        }
        float s = (ax + ay) + (az + aw);
        s += __shfl_xor(s, 1);
        s += __shfl_xor(s, 2);
        if (ql == 0) ghl[row] = s + bh;
        __syncthreads();
        float hnew = 0.f;
        if (tid < 32) {
            const float* gt_ = gil + t * 96;
            const float r = sigmoidf_(gt_[tid] + ghl[tid]);
            const float z = sigmoidf_(gt_[32 + tid] + ghl[32 + tid]);
            const float n = tanhf(gt_[64 + tid] + r * ghl[64 + tid]);
            hnew = (1.f - z) * n + z * hold;
            if (t == len - 1) hfin = hnew;
        }
        if (tid < 64 && t < len - 1) {
            const float a0 = __shfl(hnew, 2 * (tid & 15));
            const float a1 = __shfl(hnew, 2 * (tid & 15) + 1);
            if (tid < 16) {
                unsigned long long* dst =
                    (unsigned long long*)(hg + (size_t)t * (Q_TOT * H_DIM) + q * H_DIM + (b << 5));
                __hip_atomic_store(dst + tid, pack2(a0, a1), __ATOMIC_RELAXED, __HIP_MEMORY_SCOPE_AGENT);
            }
        }
    }

    if (tid < 32)
        __hip_atomic_store(&hbuf[q * H_DIM + (b << 5) + tid], hfin,
                           __ATOMIC_RELAXED, __HIP_MEMORY_SCOPE_AGENT);
    asm volatile("s_waitcnt vmcnt(0)" ::: "memory");
    __syncthreads();
    if (tid == 0)
        __hip_atomic_fetch_add(&qdone[q], 1, __ATOMIC_RELAXED, __HIP_MEMORY_SCOPE_AGENT);
    if (b != 0) return;

    if (tid == 0) {
        while (__hip_atomic_load(&qdone[q], __ATOMIC_RELAXED, __HIP_MEMORY_SCOPE_AGENT) < 8)
            __builtin_amdgcn_s_sleep(2);
    }
    __syncthreads();
    float* hql = gil;
    float* t1l = gil + 256;
    float* lgl = gil + 320;
    if (tid < H_DIM)
        hql[tid] = __hip_atomic_load(&hbuf[q * H_DIM + tid], __ATOMIC_RELAXED, __HIP_MEMORY_SCOPE_AGENT);
    __syncthreads();
    if (tid < 256) {
        const int c = tid >> 2, qq = tid & 3;
        float a = 0.f;
        #pragma unroll 8
        for (int j = 0; j < 64; ++j) {
            const int k = (qq << 6) + j;
            a = fmaf(w1t[k * D_LANG + c], hql[k], a);
        }
        a += __shfl_xor(a, 1);
        a += __shfl_xor(a, 2);
        if (qq == 0) t1l[c] = fmaxf(a + b1[c], 0.f);
    }
    __syncthreads();
    if (tid < 256) {
        const int c = tid >> 2, qq = tid & 3;
        float a = 0.f;
        #pragma unroll
        for (int j = 0; j < 16; ++j) {
            const int k = (qq << 4) + j;
            a = fmaf(w2t[k * D_LANG + c], t1l[k], a);
        }
        a += __shfl_xor(a, 1);
        a += __shfl_xor(a, 2);
        if (qq == 0) lgl[c] = a + b2[c];
    }
    __syncthreads();
    if (tid < 256) {
        const int d = tid >> 1, hh = tid & 1;
        float a = 0.f;
        #pragma unroll 8
        for (int j = 0; j < 32; ++j) {
            const int k = (hh << 5) + j;
            a = fmaf(fwt[(D_CAT + k) * D_FUSE + d], lgl[k], a);
        }
        a += __shfl_xor(a, 1);
        if (hh == 0) langc[q * D_FUSE + d] = a + fuse_b[d];
    }
}

// ---------------------------------------------------------------- k_tail v2: chunked tickets, no smask phase
__global__ __launch_bounds__(256, 3) void k_tail(const float* __restrict__ feat,
                                                 const float* __restrict__ coords,
                                                 const int* __restrict__ grps,
                                                 const float* __restrict__ langc,
                                                 const float* __restrict__ fwt,
                                                 const float* __restrict__ wdr_g,
                                                 const float* __restrict__ heat_b,
                                                 float* __restrict__ grp_part,
                                                 int* __restrict__ cnt_part,
                                                 float* __restrict__ grp2,
                                                 int* __restrict__ cnt2,
                                                 int* __restrict__ best,
                                                 const int* __restrict__ supervox,
                                                 const int* __restrict__ gt,
                                                 float* __restrict__ out,
                                                 int* __restrict__ syncs) {
    int* interG = syncs;
    int* unionG = syncs + 32;
    int* t_out  = syncs + 64;
    int* gtick  = syncs + 65;
    int* qtick  = syncs + 98;
    const int tid = threadIdx.x;
    const int bid = blockIdx.x;

    __shared__ __align__(16) float svin[SCHUNK][68];
    __shared__ __align__(16) float svp[SCHUNK][132];
    __shared__ float score[SCHUNK][Q_TOT];
    __shared__ int grps_l[SCHUNK];
    __shared__ float ps[4][G_TOT];
    __shared__ int   pc[4][G_TOT];
    __shared__ float sc[G_TOT];
    __shared__ int bl[Q_TOT];
    __shared__ int gm[G_TOT];
    __shared__ int bi_s[Q_TOT], bu_s[Q_TOT];
    __shared__ int islast;

    // ================= phase F: per-tile fused score + group partials
    {
        const int s0 = bid * SCHUNK;
        const int dsl = tid & 7, q = tid >> 3;
        float lc[16], wdr[16];
        #pragma unroll
        for (int i = 0; i < 16; ++i) {
            const int d = dsl * 16 + i;
            lc[i]  = langc[q * D_FUSE + d];
            wdr[i] = wdr_g[d];
        }
        const float hbd = heat_b[1] - heat_b[0];

        for (int i = tid; i < SCHUNK * D_SV; i += 256) {
            const int r = i >> 6, c = i & 63;
            svin[r][c] = feat[(s0 + r) * D_SV + c];
        }
        if (tid < SCHUNK * 3) { const int r = tid / 3, c = tid % 3; svin[r][D_SV + c] = coords[(s0 + r) * 3 + c]; }
        if (tid < SCHUNK) grps_l[tid] = grps[s0 + tid];
        __syncthreads();

        {
            const int d = tid & 127, sl0 = tid >> 7;
            float acc[16];
            #pragma unroll
            for (int i = 0; i < 16; ++i) acc[i] = 0.f;
            for (int k4 = 0; k4 < 16; ++k4) {
                const float w0 = fwt[(4 * k4 + 0) * D_FUSE + d];
                const float w1 = fwt[(4 * k4 + 1) * D_FUSE + d];
                const float w2 = fwt[(4 * k4 + 2) * D_FUSE + d];
                const float w3 = fwt[(4 * k4 + 3) * D_FUSE + d];
                #pragma unroll
                for (int i = 0; i < 16; ++i) {
                    const float4 xv = *(const float4*)&svin[sl0 + 2 * i][4 * k4];
                    acc[i] = fmaf(xv.x, w0, fmaf(xv.y, w1, fmaf(xv.z, w2, fmaf(xv.w, w3, acc[i]))));
                }
            }
            for (int k = 64; k < D_CAT; ++k) {
                const float wv = fwt[k * D_FUSE + d];
                #pragma unroll
                for (int i = 0; i < 16; ++i)
                    acc[i] = fmaf(svin[sl0 + 2 * i][k], wv, acc[i]);
            }
            #pragma unroll
            for (int i = 0; i < 16; ++i) svp[sl0 + 2 * i][d] = acc[i];
        }
        __syncthreads();

        for (int sl = 0; sl < SCHUNK; ++sl) {
            const float4* sv4 = (const float4*)(&svp[sl][dsl * 16]);
            float part = 0.f;
            #pragma unroll
            for (int j = 0; j < 4; ++j) {
                const float4 v = sv4[j];
                part = fmaf(fmaxf(v.x + lc[4*j+0], 0.f), wdr[4*j+0], part);
                part = fmaf(fmaxf(v.y + lc[4*j+1], 0.f), wdr[4*j+1], part);
                part = fmaf(fmaxf(v.z + lc[4*j+2], 0.f), wdr[4*j+2], part);
                part = fmaf(fmaxf(v.w + lc[4*j+3], 0.f), wdr[4*j+3], part);
            }
            part += __shfl_xor(part, 1);
            part += __shfl_xor(part, 2);
            part += __shfl_xor(part, 4);
            if (dsl == 0) score[sl][q] = sigmoidf_(part + hbd);
        }
        __syncthreads();

        for (int i = 0; i < 8; ++i) {
            const int cell = tid + 256 * i;
            const int qq = cell >> 6, g = cell & 63;
            float sum = 0.f;
            #pragma unroll
            for (int sl = 0; sl < SCHUNK; ++sl)
                sum += (grps_l[sl] == g) ? score[sl][qq] : 0.f;
            __hip_atomic_store(&grp_part[bid * (Q_TOT * G_TOT) + cell], sum,
                               __ATOMIC_RELAXED, __HIP_MEMORY_SCOPE_AGENT);
            if (cell < G_TOT) {
                int c = 0;
                #pragma unroll
                for (int sl = 0; sl < SCHUNK; ++sl) c += (grps_l[sl] == g);
                __hip_atomic_store(&cnt_part[bid * G_TOT + g], c,
                                   __ATOMIC_RELAXED, __HIP_MEMORY_SCOPE_AGENT);
            }
        }
        // bump this tile's chunk ticket (line-spaced)
        asm volatile("s_waitcnt vmcnt(0)" ::: "memory");
        __syncthreads();
        if (tid == 0)
            __hip_atomic_fetch_add(&syncs[160 + 32 * (bid / PTILES)], 1,
                                   __ATOMIC_RELAXED, __HIP_MEMORY_SCOPE_AGENT);
    }

    // ================= phase A: two-stage reduction + argmax (blocks 0..511)
    if (bid < Q_TOT * PCHUNK) {
        const int q = bid & 31, c = bid >> 5;
        const int b0 = c * PTILES;
        int b1 = b0 + PTILES; if (b1 > NBLK3) b1 = NBLK3;
        // wait only for THIS chunk's tiles
        if (tid == 0) {
            int* tc = &syncs[160 + 32 * c];
            const int tgt = b1 - b0;
            while (__hip_atomic_load(tc, __ATOMIC_RELAXED, __HIP_MEMORY_SCOPE_AGENT) < tgt)
                __builtin_amdgcn_s_sleep(4);
        }
        __syncthreads();
        const int bq = tid >> 6, g = tid & 63;
        float acc = 0.f; int cacc = 0;
        for (int b = b0 + bq; b < b1; b += 4) {
            acc  += grp_part[b * (Q_TOT * G_TOT) + q * G_TOT + g];
            cacc += cnt_part[b * G_TOT + g];
        }
        ps[bq][g] = acc; pc[bq][g] = cacc;
        __syncthreads();
        if (tid < G_TOT) {
            const float s = ((ps[0][tid] + ps[1][tid]) + ps[2][tid]) + ps[3][tid];
            const int  cc = ((pc[0][tid] + pc[1][tid]) + pc[2][tid]) + pc[3][tid];
            __hip_atomic_store(&grp2[(c * Q_TOT + q) * G_TOT + tid], s,
                               __ATOMIC_RELAXED, __HIP_MEMORY_SCOPE_AGENT);
            __hip_atomic_store(&cnt2[(c * Q_TOT + q) * G_TOT + tid], cc,
                               __ATOMIC_RELAXED, __HIP_MEMORY_SCOPE_AGENT);
        }
        __shared__ int myturn;
        asm volatile("s_waitcnt vmcnt(0)" ::: "memory");
        if (tid == 0) {
            const int old = __hip_atomic_fetch_add(&qtick[q], 1, __ATOMIC_RELAXED, __HIP_MEMORY_SCOPE_AGENT);
            myturn = (old == PCHUNK - 1) ? 1 : 0;
        }
        __syncthreads();
        if (myturn) {
            if (tid < G_TOT) {
                float s = 0.f; int cc = 0;
                #pragma unroll
                for (int c2 = 0; c2 < PCHUNK; ++c2) {
                    s  += grp2[(c2 * Q_TOT + q) * G_TOT + tid];
                    cc += cnt2[(c2 * Q_TOT + q) * G_TOT + tid];
                }
                sc[tid] = s / (float)cc;
            }
            __syncthreads();
            if (tid == 0) {
                float bv = sc[0]; int bi = 0;
                for (int g2 = 1; g2 < G_TOT; ++g2) if (sc[g2] > bv) { bv = sc[g2]; bi = g2; }
                __hip_atomic_store(&best[q], bi, __ATOMIC_RELAXED, __HIP_MEMORY_SCOPE_AGENT);
                asm volatile("s_waitcnt vmcnt(0)" ::: "memory");
                const int old = __hip_atomic_fetch_add(gtick, 1, __ATOMIC_RELAXED, __HIP_MEMORY_SCOPE_AGENT);
                if (old == Q_TOT - 1) {
                    // broadcast best-ready on 8 line-spaced flags
                    #pragma unroll
                    for (int f = 0; f < 8; ++f)
                        __hip_atomic_store(&syncs[672 + 32 * f], 1,
                                           __ATOMIC_RELAXED, __HIP_MEMORY_SCOPE_AGENT);
                }
            }
        }
    }

    // ================= wait best-ready (spread flags, long backoff)
    if (tid == 0) {
        int* fl = &syncs[672 + 32 * (bid & 7)];
        while (__hip_atomic_load(fl, __ATOMIC_RELAXED, __HIP_MEMORY_SCOPE_AGENT) == 0)
            __builtin_amdgcn_s_sleep(16);
    }
    __syncthreads();

    // build per-group q-bitmask in LDS (replaces global smask entirely)
    if (tid < Q_TOT) bl[tid] = best[tid];
    __syncthreads();
    if (tid < G_TOT) {
        int m = 0;
        #pragma unroll
        for (int qq = 0; qq < Q_TOT; ++qq) m |= (bl[qq] == tid) ? (1 << qq) : 0;
        gm[tid] = m;
    }
    __syncthreads();

    // ================= phase O: obj_pts + inter/union + iou
    {
        const int gidx = bid * 256 + tid;
        const int q4 = (gidx & 7) * 4;
        const int nstride = (NBLK3 * 256) >> 3;    // 20000
        int a0 = 0, a1 = 0, a2 = 0, a3 = 0;
        int u0 = 0, u1 = 0, u2 = 0, u3 = 0;
        for (int n = gidx >> 3; n < N_TOT; n += nstride) {
            const int m = gm[grps[supervox[n]]];
            const int4 g4 = *(const int4*)&gt[n * Q_TOT + q4];
            const int o0 = (m >> (q4 + 0)) & 1;
            const int o1 = (m >> (q4 + 1)) & 1;
            const int o2 = (m >> (q4 + 2)) & 1;
            const int o3 = (m >> (q4 + 3)) & 1;
            *(float4*)&out[n * Q_TOT + q4] =
                make_float4((float)o0, (float)o1, (float)o2, (float)o3);
            a0 += o0 & g4.x; u0 += o0 | g4.x;
            a1 += o1 & g4.y; u1 += o1 | g4.y;
            a2 += o2 & g4.z; u2 += o2 | g4.z;
            a3 += o3 & g4.w; u3 += o3 | g4.w;
        }
        if (tid < Q_TOT) { bi_s[tid] = 0; bu_s[tid] = 0; }
        __syncthreads();
        atomicAdd(&bi_s[q4 + 0], a0); atomicAdd(&bu_s[q4 + 0], u0);
        atomicAdd(&bi_s[q4 + 1], a1); atomicAdd(&bu_s[q4 + 1], u1);
        atomicAdd(&bi_s[q4 + 2], a2); atomicAdd(&bu_s[q4 + 2], u2);
        atomicAdd(&bi_s[q4 + 3], a3); atomicAdd(&bu_s[q4 + 3], u3);
        __syncthreads();
        if (tid < Q_TOT) { atomicAdd(&interG[tid], bi_s[tid]); atomicAdd(&unionG[tid], bu_s[tid]); }
        asm volatile("s_waitcnt vmcnt(0)" ::: "memory");
        if (tid == 0) {
            const int old = __hip_atomic_fetch_add(t_out, 1, __ATOMIC_RELAXED, __HIP_MEMORY_SCOPE_AGENT);
            islast = (old == NBLK3 - 1) ? 1 : 0;
        }
        __syncthreads();
        if (islast && tid < Q_TOT) {
            const int iv = __hip_atomic_load(&interG[tid], __ATOMIC_RELAXED, __HIP_MEMORY_SCOPE_AGENT);
            const int uv = __hip_atomic_load(&unionG[tid], __ATOMIC_RELAXED, __HIP_MEMORY_SCOPE_AGENT);
            out[(size_t)N_TOT * Q_TOT + tid] = (float)iv / ((float)uv + 1e-5f);
        }
    }
}

extern "C" void kernel_launch(void* const* d_in, const int* in_sizes, int n_in,
                              void* d_out, int out_size, void* d_ws, size_t ws_size,
                              hipStream_t stream) {
    const float* lang_feat = (const float*)d_in[0];
    const float* feat      = (const float*)d_in[1];
    const float* coords    = (const float*)d_in[2];
    const int*   lang_len  = (const int*)d_in[3];
    const int*   grps      = (const int*)d_in[4];
    const int*   supervox  = (const int*)d_in[5];
    const int*   gt        = (const int*)d_in[6];
    const float* w_ih      = (const float*)d_in[7];
    const float* w_hh      = (const float*)d_in[8];
    const float* b_ih      = (const float*)d_in[9];
    const float* b_hh      = (const float*)d_in[10];
    const float* sqz_w1    = (const float*)d_in[11];
    const float* sqz_b1    = (const float*)d_in[12];
    const float* sqz_w2    = (const float*)d_in[13];
    const float* sqz_b2    = (const float*)d_in[14];
    const float* fuse_w    = (const float*)d_in[15];
    const float* fuse_b    = (const float*)d_in[16];
    const float* heat_w    = (const float*)d_in[17];
    const float* heat_b    = (const float*)d_in[18];
    float* out = (float*)d_out;

    float* gi       = (float*)d_ws;                       // 737280
    float* hbuf     = gi + 737280;                        // 8192
    float* langc    = hbuf + 8192;                        // 4096
    float* grp_part = langc + 4096;                       // 1280000
    int*   cnt_part = (int*)(grp_part + NBLK3 * 2048);    // 40000
    int*   best     = cnt_part + NBLK3 * 64;              // 32
    int*   syncs    = best + 32;                          // SYNCS_N
    float* hg       = (float*)(syncs + SYNCS_N);          // 245760
    float* fwt      = hg + HG_ELEMS;                      // 16768
    float* w1t      = fwt + FW_LD * D_FUSE;               // 16384
    float* w2t      = w1t + H_DIM * D_LANG;               // 4096
    float* wdr      = w2t + D_LANG * D_LANG;              // 128
    float* grp2     = wdr + 128;                          // 32768
    int*   cnt2     = (int*)(grp2 + PCHUNK * Q_TOT * G_TOT); // 32768

    k_gi   <<<GI_GRID + 9, 128, 0, stream>>>(lang_feat, w_ih, b_ih, fuse_w, sqz_w1, sqz_w2, heat_w,
                                             gi, fwt, w1t, w2t, wdr, hg, syncs);
    k_gru8 <<<Q_TOT * 8, 384, 0, stream>>>(gi, w_hh, b_hh, lang_len, hg, hbuf,
                                           w1t, sqz_b1, w2t, sqz_b2, fwt, fuse_b, langc,
                                           syncs + 66);
    k_tail <<<NBLK3, 256, 0, stream>>>(feat, coords, grps, langc, fwt, wdr, heat_b,
                                       grp_part, cnt_part, grp2, cnt2, best,
                                       supervox, gt, out, syncs);
}